// Round 11
// baseline (287.564 us; speedup 1.0000x reference)
//
#include <hip/hip_runtime.h>
#include <hip/hip_bf16.h>
#include <cstdint>
#include <cmath>

#define B_ 4
#define T_ 2048
#define C_ 768
#define H_ 12
#define D_ 64
#define MLP_ 3072
#define BT_ (B_*T_)

typedef __hip_bfloat16 hbf;
typedef __bf16 bf16_t;
typedef bf16_t bf16x8 __attribute__((ext_vector_type(8)));
typedef bf16_t bf16x4 __attribute__((ext_vector_type(4)));
typedef float f32x4 __attribute__((ext_vector_type(4)));

static __device__ __forceinline__ void load_lds16(const void* g, void* l) {
    __builtin_amdgcn_global_load_lds(
        (const __attribute__((address_space(1))) unsigned int*)g,
        (__attribute__((address_space(3))) unsigned int*)l, 16, 0, 0);
}

// ---------------- LDS-tiled transpose: f32 [R][S] -> bf16 [S][R] ----------------
__global__ __launch_bounds__(256) void transpose_pack(
    const float* __restrict__ src, hbf* __restrict__ dst, int R, int S)
{
    __shared__ float tl[64 * 65];
    src += (size_t)blockIdx.z * R * S;
    dst += (size_t)blockIdx.z * R * S;
    const int r0 = blockIdx.y * 64, s0 = blockIdx.x * 64;
    const int c = threadIdx.x & 63, q = threadIdx.x >> 6;
#pragma unroll
    for (int j = 0; j < 16; ++j) {
        int r = q + j * 4;
        tl[r * 65 + c] = src[(size_t)(r0 + r) * S + s0 + c];
    }
    __syncthreads();
#pragma unroll
    for (int j = 0; j < 16; ++j) {
        int s = q + j * 4;
        dst[(size_t)(s0 + s) * R + r0 + c] = __float2bfloat16(tl[c * 65 + s]);
    }
}

// Combined q/k/v weight pack: 36 z-slices of [768][64] -> rows of WqkT [2304][768].
__global__ __launch_bounds__(256) void pack_qkv3(
    const float* __restrict__ Wq, const float* __restrict__ Wk,
    const float* __restrict__ Wv, hbf* __restrict__ WqkT)
{
    __shared__ float tl[64 * 65];
    const int z = blockIdx.z;
    const int mtx = z / 12, head = z - mtx * 12;
    const float* src = (mtx == 0 ? Wq : mtx == 1 ? Wk : Wv) + (size_t)head * 49152;
    hbf* dst = WqkT + (size_t)z * 49152;
    const int r0 = blockIdx.y * 64;
    const int c = threadIdx.x & 63, q = threadIdx.x >> 6;
#pragma unroll
    for (int j = 0; j < 16; ++j) {
        int r = q + j * 4;
        tl[r * 65 + c] = src[(size_t)(r0 + r) * 64 + c];
    }
    __syncthreads();
#pragma unroll
    for (int j = 0; j < 16; ++j) {
        int s = q + j * 4;
        dst[(size_t)s * 768 + r0 + c] = __float2bfloat16(tl[c * 65 + s]);
    }
}

// ---------------- layernorm (row = 768), templated input type ----------------
template<typename TI>
__global__ __launch_bounds__(256) void ln_kernel(
    const TI* __restrict__ x, const float* __restrict__ g,
    const float* __restrict__ bb, hbf* __restrict__ out)
{
    __shared__ float red[8];
    const int row = blockIdx.x;
    const TI* xr = x + (size_t)row * C_;
    const int t = threadIdx.x;
    float v0, v1, v2;
    if constexpr (__is_same(TI, float)) {
        v0 = xr[t]; v1 = xr[t + 256]; v2 = xr[t + 512];
    } else {
        v0 = __bfloat162float(xr[t]);
        v1 = __bfloat162float(xr[t + 256]);
        v2 = __bfloat162float(xr[t + 512]);
    }
    float s = v0 + v1 + v2;
    float s2 = v0 * v0 + v1 * v1 + v2 * v2;
#pragma unroll
    for (int m = 1; m < 64; m <<= 1) {
        s  += __shfl_xor(s,  m, 64);
        s2 += __shfl_xor(s2, m, 64);
    }
    if ((t & 63) == 0) { red[t >> 6] = s; red[4 + (t >> 6)] = s2; }
    __syncthreads();
    float S  = red[0] + red[1] + red[2] + red[3];
    float S2 = red[4] + red[5] + red[6] + red[7];
    float mu  = S * (1.0f / C_);
    float var = S2 * (1.0f / C_) - mu * mu;
    float inv = rsqrtf(var + 1e-6f);
    hbf* orow = out + (size_t)row * C_;
    orow[t]       = __float2bfloat16((v0 - mu) * inv * g[t]       + bb[t]);
    orow[t + 256] = __float2bfloat16((v1 - mu) * inv * g[t + 256] + bb[t + 256]);
    orow[t + 512] = __float2bfloat16((v2 - mu) * inv * g[t + 512] + bb[t + 512]);
}

// ---------------- GEMM: C[M,N] = A[M,K](bf16) * Bt[N,K](bf16)^T ----------------
// BK=64, tile 128xTN, XOR-swizzled LDS, 2-barrier loop, 1D grid + XCD swizzle.
// TN=128: single LDS buffer (32 KB, 3 blocks/CU).
// TN=64 : DOUBLE-buffered (48 KB, still 3 blocks/CU) — stage(next) issued
//         before compute(cur), hiding the load latency within the block.
template<int EPI, int TN>
__global__ __launch_bounds__(256, (TN == 64) ? 3 : 3) void gemm_kernel(
    const hbf* __restrict__ A, const hbf* __restrict__ Bt,
    float* __restrict__ outF, hbf* __restrict__ outH,
    const float* __restrict__ bias, const float* __restrict__ residF,
    const hbf* __restrict__ residH,
    int M, int N, int K,
    hbf* __restrict__ qb, hbf* __restrict__ kb, hbf* __restrict__ vt,
    float scale, int gx)
{
    constexpr bool DBUF = (TN == 64);
    constexpr int AM = (TN == 128) ? 4 : 2;     // m-frags per wave
    constexpr int NB_B = (TN == 128) ? 4 : 2;   // B staging iters
    constexpr int ABYTES = 128 * 64 * 2;        // 16 KB per A buffer
    constexpr int BBYTES = TN * 64 * 2;         // 16/8 KB per B buffer
    __shared__ hbf sA[(DBUF ? 2 : 1) * 128 * 64];
    __shared__ hbf sB[(DBUF ? 2 : 1) * TN * 64];
    const int tid = threadIdx.x;
    const int lane = tid & 63;
    const int wid = tid >> 6;
    const int lr = lane & 15, hg = lane >> 4;
    const int bid = blockIdx.x, nwg = gridDim.x;
    const int wg = (bid & 7) * (nwg >> 3) + (bid >> 3);
    const int bx = wg % gx, by = wg / gx;
    const int row0 = by * 128;
    const int col0 = bx * TN;
    const int wrow = (TN == 128) ? (wid >> 1) * 64 : wid * 32;
    const int wcol = (TN == 128) ? (wid & 1) * 64 : 0;

    f32x4 acc[AM][4] = {};

    int offG[4];
    const int Kb = K * 2;
#pragma unroll
    for (int i = 0; i < 4; ++i) {
        int c = tid + i * 256;
        offG[i] = (c >> 3) * Kb + (((c & 7) ^ ((c >> 3) & 7)) << 4);
    }
    const char* gA = (const char*)(A + (size_t)row0 * K);
    const char* gB = (const char*)(Bt + (size_t)col0 * K);

    auto stage = [&](int kt, int which) {
        const int kb2 = kt * 128;
        char* dA = (char*)sA + which * ABYTES;
        char* dB = (char*)sB + which * BBYTES;
#pragma unroll
        for (int i = 0; i < 4; ++i)
            load_lds16(gA + (size_t)(offG[i] + kb2), dA + i * 4096 + wid * 1024);
#pragma unroll
        for (int i = 0; i < NB_B; ++i)
            load_lds16(gB + (size_t)(offG[i] + kb2), dB + i * 4096 + wid * 1024);
    };
    auto compute = [&](int which) {
        const char* cA = (const char*)sA + which * ABYTES;
        const char* cB = (const char*)sB + which * BBYTES;
#pragma unroll
        for (int kf = 0; kf < 2; ++kf) {
            const int sl = ((kf * 4 + hg) ^ (lr & 7)) << 4;
            bf16x8 af[AM], bfr[4];
#pragma unroll
            for (int m = 0; m < AM; ++m)
                af[m] = *(const bf16x8*)(cA + (wrow + m * 16 + lr) * 128 + sl);
#pragma unroll
            for (int n = 0; n < 4; ++n)
                bfr[n] = *(const bf16x8*)(cB + (wcol + n * 16 + lr) * 128 + sl);
#pragma unroll
            for (int m = 0; m < AM; ++m)
#pragma unroll
                for (int n = 0; n < 4; ++n)
                    acc[m][n] = __builtin_amdgcn_mfma_f32_16x16x32_bf16(af[m], bfr[n], acc[m][n], 0, 0, 0);
        }
    };

    const int NK = K >> 6;          // 12 or 48, always even
    if constexpr (DBUF) {
        stage(0, 0);
        __syncthreads();
        for (int kt = 0; kt < NK; kt += 2) {
            stage(kt + 1, 1);          // kt+1 < NK (NK even)
            compute(0);
            __syncthreads();           // drains stage(kt+1); all waves done with buf0
            if (kt + 2 < NK) stage(kt + 2, 0);
            compute(1);
            __syncthreads();
        }
    } else {
        stage(0, 0);
        for (int kt = 0; kt < NK; ++kt) {
            __syncthreads();           // drains staged loads
            compute(0);
            __syncthreads();           // all waves done reading before restage
            if (kt + 1 < NK) stage(kt + 1, 0);
        }
    }

#pragma unroll
    for (int m = 0; m < AM; ++m) {
#pragma unroll
        for (int n = 0; n < 4; ++n) {
            const int colc = col0 + wcol + n * 16 + lr;
            const int rowb = row0 + wrow + m * 16 + hg * 4;
            if constexpr (EPI == 3) {
                if (colc >= 2 * C_) {
                    bf16x4 w;
#pragma unroll
                    for (int j = 0; j < 4; ++j) w[j] = (bf16_t)acc[m][n][j];
                    *(bf16x4*)(vt + (size_t)(colc - 2 * C_) * BT_ + rowb) = w;
                    continue;
                }
            }
#pragma unroll
            for (int j = 0; j < 4; ++j) {
                int row = rowb + j;
                int col = colc;
                float v = acc[m][n][j];
                if constexpr (EPI == 0) {
                    outH[(size_t)row * N + col] = __float2bfloat16(v);
                } else if constexpr (EPI == 2) {
                    float tt = v + bias[col];
                    float ge = 0.5f * tt * (1.0f + erff(tt * 0.70710678118654752f));
                    outH[(size_t)row * N + col] = __float2bfloat16(ge);
                } else if constexpr (EPI == 3) {
                    int typ = col / C_;            // 0=q, 1=k (v handled above)
                    int rr = col - typ * C_;
                    int h = rr >> 6, d = rr & 63;
                    int b = row >> 11, t = row & (T_ - 1);
                    size_t bh = (size_t)b * H_ + h;
                    if (typ == 0) qb[(bh * T_ + t) * D_ + d] = __float2bfloat16(v * scale);
                    else          kb[(bh * T_ + t) * D_ + d] = __float2bfloat16(v);
                } else if constexpr (EPI == 4) {
                    outH[(size_t)row * N + col] =
                        __float2bfloat16(v + bias[col] + residF[(size_t)row * N + col]);
                } else {  // EPI == 5
                    outF[(size_t)row * N + col] =
                        v + bias[col] + __bfloat162float(residH[(size_t)row * N + col]);
                }
            }
        }
    }
}

// ---------------- flash attention (swapped QK^T, defer-max, raw exp2) ----------
// 1D grid 768 (XCD-swizzled). 4 waves x 32 q-rows. q pre-scaled by
// 768^-0.5 * log2(e) -> scores in log2 domain; P = v_exp_f32(st - m) directly
// (single trans instruction, no v_mul — avoids r5's libm exp2f fixup path).
// Denominator l = P.1 via MFMA ones-fragment (layout matches o; no broadcasts).
__global__ __launch_bounds__(256, 3) void attn_kernel(
    const hbf* __restrict__ qg, const hbf* __restrict__ kg,
    const hbf* __restrict__ vg, hbf* __restrict__ outA)
{
    __shared__ hbf sK0[64 * 64], sK1[64 * 64];   // [s][d], swizzled
    __shared__ hbf sV0[64 * 64], sV1[64 * 64];   // [d][s], swizzled
    __shared__ hbf sP[4 * 32 * 64];              // per wave [q=32][kv=64], swizzled
    const int tid = threadIdx.x, lane = tid & 63, wid = tid >> 6;
    const int lr = lane & 15, hg = lane >> 4;
    const int wg = (blockIdx.x & 7) * 96 + (blockIdx.x >> 3);   // 768/8 = 96
    const int bh = wg >> 4;
    const int b = bh / H_, h = bh - b * H_;
    const int wr0 = (wg & 15) * 128 + wid * 32;
    const hbf* qbh = qg + (size_t)bh * T_ * D_;
    const hbf* kbh = kg + (size_t)bh * T_ * D_;
    const hbf* vbh = vg + (size_t)h * 64 * BT_ + (size_t)b * T_;

    bf16x8 a_q[2][2];
#pragma unroll
    for (int m = 0; m < 2; ++m)
#pragma unroll
        for (int kf = 0; kf < 2; ++kf)
            a_q[m][kf] = *(const bf16x8*)(qbh + (size_t)(wr0 + m * 16 + lr) * D_ + kf * 32 + hg * 8);

    bf16x8 vone;
#pragma unroll
    for (int i = 0; i < 8; ++i) vone[i] = (bf16_t)1.0f;

    f32x4 o[2][4] = {};
    f32x4 lden[2] = {};            // row-sum accumulator, same layout as o
    float mreg[2] = {-3e38f, -3e38f};

    int offK[2], offV[2];
#pragma unroll
    for (int i = 0; i < 2; ++i) {
        int c = tid + i * 256;
        int sw = ((c & 7) ^ ((c >> 3) & 7)) << 4;
        offK[i] = (c >> 3) * 128 + sw;
        offV[i] = (c >> 3) * (BT_ * 2) + sw;
    }
    hbf* sPw = sP + wid * (32 * 64);
    const int sl0 = ((0 * 4 + hg) ^ (lr & 7)) << 4;
    const int sl1 = ((1 * 4 + hg) ^ (lr & 7)) << 4;
    const int bcast = hg * 20;   // source lane hg*16 + (hg*4): for fb[j] add j

    auto stage = [&](int itn, hbf* sKd, hbf* sVd) {
        const char* kp = (const char*)kbh + (size_t)itn * 8192;
        const char* vp = (const char*)vbh + (size_t)itn * 128;
#pragma unroll
        for (int i = 0; i < 2; ++i) {
            load_lds16(kp + offK[i], (char*)sKd + i * 4096 + wid * 1024);
            load_lds16(vp + offV[i], (char*)sVd + i * 4096 + wid * 1024);
        }
    };

    auto tile = [&](const hbf* sKc, const hbf* sVc) {
        f32x4 st[4][2] = {};
        __builtin_amdgcn_s_setprio(1);
#pragma unroll
        for (int kf = 0; kf < 2; ++kf) {
            const int sl = kf ? sl1 : sl0;
#pragma unroll
            for (int n = 0; n < 4; ++n) {
                bf16x8 ak = *(const bf16x8*)((const char*)sKc + (n * 16 + lr) * 128 + sl);
                st[n][0] = __builtin_amdgcn_mfma_f32_16x16x32_bf16(ak, a_q[0][kf], st[n][0], 0, 0, 0);
                st[n][1] = __builtin_amdgcn_mfma_f32_16x16x32_bf16(ak, a_q[1][kf], st[n][1], 0, 0, 0);
            }
        }
        __builtin_amdgcn_s_setprio(0);

#pragma unroll
        for (int m = 0; m < 2; ++m) {
            // balanced max tree (depth 4) over the 16 in-lane values
            f32x4 mx = st[0][m];
            mx[0] = fmaxf(mx[0], st[1][m][0]); mx[1] = fmaxf(mx[1], st[1][m][1]);
            mx[2] = fmaxf(mx[2], st[1][m][2]); mx[3] = fmaxf(mx[3], st[1][m][3]);
            f32x4 my = st[2][m];
            my[0] = fmaxf(my[0], st[3][m][0]); my[1] = fmaxf(my[1], st[3][m][1]);
            my[2] = fmaxf(my[2], st[3][m][2]); my[3] = fmaxf(my[3], st[3][m][3]);
            float t01 = fmaxf(fmaxf(mx[0], my[0]), fmaxf(mx[1], my[1]));
            float t23 = fmaxf(fmaxf(mx[2], my[2]), fmaxf(mx[3], my[3]));
            float t = fmaxf(t01, t23);
            t = fmaxf(t, __shfl_xor(t, 16, 64));
            t = fmaxf(t, __shfl_xor(t, 32, 64));
            if (__any(t - mreg[m] > 11.5415603f)) {   // 8*log2(e): rarely taken
                float nm = fmaxf(mreg[m], t);
                float fac = __builtin_amdgcn_exp2f(mreg[m] - nm);
                mreg[m] = nm;
                float fb[4];
#pragma unroll
                for (int j = 0; j < 4; ++j)
                    fb[j] = __shfl(fac, bcast + j, 64);
#pragma unroll
                for (int j = 0; j < 4; ++j) {
                    lden[m][j] *= fb[j];
#pragma unroll
                    for (int nd = 0; nd < 4; ++nd)
                        o[m][nd][j] *= fb[j];
                }
            }
            const int r = m * 16 + lr;
#pragma unroll
            for (int n = 0; n < 4; ++n) {
                float p0 = __builtin_amdgcn_exp2f(st[n][m][0] - mreg[m]);
                float p1 = __builtin_amdgcn_exp2f(st[n][m][1] - mreg[m]);
                float p2 = __builtin_amdgcn_exp2f(st[n][m][2] - mreg[m]);
                float p3 = __builtin_amdgcn_exp2f(st[n][m][3] - mreg[m]);
                bf16x4 w;
                w[0] = (bf16_t)p0; w[1] = (bf16_t)p1; w[2] = (bf16_t)p2; w[3] = (bf16_t)p3;
                *(bf16x4*)((char*)sPw + r * 128 +
                           (((n * 2 + (hg >> 1)) ^ (r & 7)) << 4) + ((hg & 1) * 8)) = w;
            }
        }

        // PV + MFMA row-sum (l = P.1) — P is wave-private, no block barrier
        __builtin_amdgcn_s_setprio(1);
#pragma unroll
        for (int kf = 0; kf < 2; ++kf) {
            const int sl = kf ? sl1 : sl0;
            bf16x8 ap0 = *(const bf16x8*)((const char*)sPw + lr * 128 + sl);
            bf16x8 ap1 = *(const bf16x8*)((const char*)sPw + (16 + lr) * 128 + sl);
            lden[0] = __builtin_amdgcn_mfma_f32_16x16x32_bf16(ap0, vone, lden[0], 0, 0, 0);
            lden[1] = __builtin_amdgcn_mfma_f32_16x16x32_bf16(ap1, vone, lden[1], 0, 0, 0);
#pragma unroll
            for (int nd = 0; nd < 4; ++nd) {
                bf16x8 bv = *(const bf16x8*)((const char*)sVc + (nd * 16 + lr) * 128 + sl);
                o[0][nd] = __builtin_amdgcn_mfma_f32_16x16x32_bf16(ap0, bv, o[0][nd], 0, 0, 0);
                o[1][nd] = __builtin_amdgcn_mfma_f32_16x16x32_bf16(ap1, bv, o[1][nd], 0, 0, 0);
            }
        }
        __builtin_amdgcn_s_setprio(0);
    };

    const int NT = T_ / 64;   // 32, even
    stage(0, sK0, sV0);
    __syncthreads();
    for (int it = 0; it < NT; it += 2) {
        stage(it + 1, sK1, sV1);
        tile(sK0, sV0);
        __syncthreads();
        if (it + 2 < NT) stage(it + 2, sK0, sV0);
        tile(sK1, sV1);
        __syncthreads();
    }

    // epilogue: l already in o's layout — direct divide, no broadcast
#pragma unroll
    for (int m = 0; m < 2; ++m) {
        f32x4 rinv;
#pragma unroll
        for (int j = 0; j < 4; ++j) rinv[j] = 1.0f / lden[m][j];
#pragma unroll
        for (int nd = 0; nd < 4; ++nd)
#pragma unroll
            for (int j = 0; j < 4; ++j) {
                int row = wr0 + m * 16 + hg * 4 + j;
                int col = nd * 16 + lr;
                outA[((size_t)(b * T_ + row)) * C_ + h * D_ + col] =
                    __float2bfloat16(o[m][nd][j] * rinv[j]);
            }
    }
}

// ---------------- launch ----------------
extern "C" void kernel_launch(void* const* d_in, const int* in_sizes, int n_in,
                              void* d_out, int out_size, void* d_ws, size_t ws_size,
                              hipStream_t stream)
{
    const float* x    = (const float*)d_in[0];
    const float* Wq   = (const float*)d_in[1];
    const float* Wk   = (const float*)d_in[2];
    const float* Wv   = (const float*)d_in[3];
    const float* Wo   = (const float*)d_in[4];
    const float* bo   = (const float*)d_in[5];
    const float* ln1g = (const float*)d_in[6];
    const float* ln1b = (const float*)d_in[7];
    const float* ln2g = (const float*)d_in[8];
    const float* ln2b = (const float*)d_in[9];
    const float* W1   = (const float*)d_in[10];
    const float* b1   = (const float*)d_in[11];
    const float* W2   = (const float*)d_in[12];
    const float* b2   = (const float*)d_in[13];
    float* out = (float*)d_out;
    char* ws = (char*)d_ws;

    hbf*  xn    = (hbf*)(ws + 0);            // 12.58 MB
    hbf*  WqkT  = (hbf*)(ws + 12582912);     // [2304][768] 3.54 MB (q,k,v rows)
    hbf*  qb    = (hbf*)(ws + 16121856);     // 12.58 MB
    hbf*  kb    = (hbf*)(ws + 28704768);     // 12.58 MB
    hbf*  vT    = (hbf*)(ws + 41287680);     // [768][8192] 12.58 MB
    hbf*  h1    = (hbf*)(ws + 0);            // 50.33 MB overlay (dead inputs by MLP)
    hbf*  attnB = (hbf*)(ws + 53870592);     // 12.58 MB
    hbf*  yln   = (hbf*)(ws + 53870592);     // overlays attnB
    hbf*  x2b   = (hbf*)(ws + 66453504);     // 12.58 MB (bf16 residual-1)
    hbf*  WoT   = (hbf*)(ws + 91619328);     // 1.18 MB
    hbf*  W1T   = (hbf*)(ws + 92798976);     // 4.72 MB
    hbf*  W2T   = (hbf*)(ws + 97517568);     // 4.72 MB (end 102,236,160)

    // 768^-0.5 * log2(e): QK^T scores land in log2 domain for raw v_exp_f32
    const float SCALE2 = 0.036084391824351615f * 1.4426950408889634f;

    pack_qkv3<<<dim3(1, 12, 36), 256, 0, stream>>>(Wq, Wk, Wv, WqkT);
    transpose_pack<<<dim3(12, 12, 1), 256, 0, stream>>>(Wo, WoT, 768, 768);
    transpose_pack<<<dim3(48, 12, 1), 256, 0, stream>>>(W1, W1T, 768, 3072);
    transpose_pack<<<dim3(12, 48, 1), 256, 0, stream>>>(W2, W2T, 3072, 768);
    ln_kernel<float><<<8192, 256, 0, stream>>>(x, ln1g, ln1b, xn);
    gemm_kernel<3,128><<<1152, 256, 0, stream>>>(xn, WqkT, nullptr, nullptr, nullptr, nullptr,
        nullptr, 8192, 2304, 768, qb, kb, vT, SCALE2, 18);
    attn_kernel<<<768, 256, 0, stream>>>(qb, kb, vT, attnB);
    gemm_kernel<4,64><<<768, 256, 0, stream>>>(attnB, WoT, nullptr, x2b, bo, x,
        nullptr, 8192, 768, 768, nullptr, nullptr, nullptr, 1.0f, 12);
    ln_kernel<hbf><<<8192, 256, 0, stream>>>(x2b, ln2g, ln2b, yln);
    gemm_kernel<2,128><<<1536, 256, 0, stream>>>(yln, W1T, nullptr, h1, b1, nullptr,
        nullptr, 8192, 3072, 768, nullptr, nullptr, nullptr, 1.0f, 24);
    gemm_kernel<5,64><<<768, 256, 0, stream>>>(h1, W2T, out, nullptr, b2, nullptr,
        x2b, 8192, 768, 3072, nullptr, nullptr, nullptr, 1.0f, 12);
}

// Round 12
// 277.184 us; speedup vs baseline: 1.0374x; 1.0374x over previous
//
#include <hip/hip_runtime.h>
#include <hip/hip_bf16.h>
#include <cstdint>
#include <cmath>

#define B_ 4
#define T_ 2048
#define C_ 768
#define H_ 12
#define D_ 64
#define MLP_ 3072
#define BT_ (B_*T_)

typedef __hip_bfloat16 hbf;
typedef __bf16 bf16_t;
typedef bf16_t bf16x8 __attribute__((ext_vector_type(8)));
typedef bf16_t bf16x4 __attribute__((ext_vector_type(4)));
typedef float f32x4 __attribute__((ext_vector_type(4)));

static __device__ __forceinline__ void load_lds16(const void* g, void* l) {
    __builtin_amdgcn_global_load_lds(
        (const __attribute__((address_space(1))) unsigned int*)g,
        (__attribute__((address_space(3))) unsigned int*)l, 16, 0, 0);
}

// ---------------- LDS-tiled transpose: f32 [R][S] -> bf16 [S][R] ----------------
__global__ __launch_bounds__(256) void transpose_pack(
    const float* __restrict__ src, hbf* __restrict__ dst, int R, int S)
{
    __shared__ float tl[64 * 65];
    src += (size_t)blockIdx.z * R * S;
    dst += (size_t)blockIdx.z * R * S;
    const int r0 = blockIdx.y * 64, s0 = blockIdx.x * 64;
    const int c = threadIdx.x & 63, q = threadIdx.x >> 6;
#pragma unroll
    for (int j = 0; j < 16; ++j) {
        int r = q + j * 4;
        tl[r * 65 + c] = src[(size_t)(r0 + r) * S + s0 + c];
    }
    __syncthreads();
#pragma unroll
    for (int j = 0; j < 16; ++j) {
        int s = q + j * 4;
        dst[(size_t)(s0 + s) * R + r0 + c] = __float2bfloat16(tl[c * 65 + s]);
    }
}

// Combined q/k/v weight pack: 36 z-slices of [768][64] -> rows of WqkT [2304][768].
__global__ __launch_bounds__(256) void pack_qkv3(
    const float* __restrict__ Wq, const float* __restrict__ Wk,
    const float* __restrict__ Wv, hbf* __restrict__ WqkT)
{
    __shared__ float tl[64 * 65];
    const int z = blockIdx.z;
    const int mtx = z / 12, head = z - mtx * 12;
    const float* src = (mtx == 0 ? Wq : mtx == 1 ? Wk : Wv) + (size_t)head * 49152;
    hbf* dst = WqkT + (size_t)z * 49152;
    const int r0 = blockIdx.y * 64;
    const int c = threadIdx.x & 63, q = threadIdx.x >> 6;
#pragma unroll
    for (int j = 0; j < 16; ++j) {
        int r = q + j * 4;
        tl[r * 65 + c] = src[(size_t)(r0 + r) * 64 + c];
    }
    __syncthreads();
#pragma unroll
    for (int j = 0; j < 16; ++j) {
        int s = q + j * 4;
        dst[(size_t)s * 768 + r0 + c] = __float2bfloat16(tl[c * 65 + s]);
    }
}

// ---------------- layernorm (row = 768), templated input type ----------------
template<typename TI>
__global__ __launch_bounds__(256) void ln_kernel(
    const TI* __restrict__ x, const float* __restrict__ g,
    const float* __restrict__ bb, hbf* __restrict__ out)
{
    __shared__ float red[8];
    const int row = blockIdx.x;
    const TI* xr = x + (size_t)row * C_;
    const int t = threadIdx.x;
    float v0, v1, v2;
    if constexpr (__is_same(TI, float)) {
        v0 = xr[t]; v1 = xr[t + 256]; v2 = xr[t + 512];
    } else {
        v0 = __bfloat162float(xr[t]);
        v1 = __bfloat162float(xr[t + 256]);
        v2 = __bfloat162float(xr[t + 512]);
    }
    float s = v0 + v1 + v2;
    float s2 = v0 * v0 + v1 * v1 + v2 * v2;
#pragma unroll
    for (int m = 1; m < 64; m <<= 1) {
        s  += __shfl_xor(s,  m, 64);
        s2 += __shfl_xor(s2, m, 64);
    }
    if ((t & 63) == 0) { red[t >> 6] = s; red[4 + (t >> 6)] = s2; }
    __syncthreads();
    float S  = red[0] + red[1] + red[2] + red[3];
    float S2 = red[4] + red[5] + red[6] + red[7];
    float mu  = S * (1.0f / C_);
    float var = S2 * (1.0f / C_) - mu * mu;
    float inv = rsqrtf(var + 1e-6f);
    hbf* orow = out + (size_t)row * C_;
    orow[t]       = __float2bfloat16((v0 - mu) * inv * g[t]       + bb[t]);
    orow[t + 256] = __float2bfloat16((v1 - mu) * inv * g[t + 256] + bb[t + 256]);
    orow[t + 512] = __float2bfloat16((v2 - mu) * inv * g[t + 512] + bb[t + 512]);
}

// ---------------- GEMM: C[M,N] = A[M,K](bf16) * Bt[N,K](bf16)^T ----------------
// BK=64, tile 128xTN (TN=128 or 64), XOR-swizzled LDS, SINGLE buffer,
// 2-barrier loop, 1D grid + XCD swizzle. TN=64 runs 4 blocks/CU.
// (r10-verified; explicit dbuf re-tested r11 and regressed — do not re-add.)
template<int EPI, int TN>
__global__ __launch_bounds__(256, (TN == 64) ? 4 : 3) void gemm_kernel(
    const hbf* __restrict__ A, const hbf* __restrict__ Bt,
    float* __restrict__ outF, hbf* __restrict__ outH,
    const float* __restrict__ bias, const float* __restrict__ residF,
    const hbf* __restrict__ residH,
    int M, int N, int K,
    hbf* __restrict__ qb, hbf* __restrict__ kb, hbf* __restrict__ vt,
    float scale, int gx)
{
    constexpr int AM = (TN == 128) ? 4 : 2;     // m-frags per wave
    constexpr int NB_B = (TN == 128) ? 4 : 2;   // B staging iters
    __shared__ hbf sA[128 * 64];
    __shared__ hbf sB[TN * 64];
    const int tid = threadIdx.x;
    const int lane = tid & 63;
    const int wid = tid >> 6;
    const int lr = lane & 15, hg = lane >> 4;
    const int bid = blockIdx.x, nwg = gridDim.x;
    const int wg = (bid & 7) * (nwg >> 3) + (bid >> 3);
    const int bx = wg % gx, by = wg / gx;
    const int row0 = by * 128;
    const int col0 = bx * TN;
    const int wrow = (TN == 128) ? (wid >> 1) * 64 : wid * 32;
    const int wcol = (TN == 128) ? (wid & 1) * 64 : 0;

    f32x4 acc[AM][4] = {};

    int offG[4];
    const int Kb = K * 2;
#pragma unroll
    for (int i = 0; i < 4; ++i) {
        int c = tid + i * 256;
        offG[i] = (c >> 3) * Kb + (((c & 7) ^ ((c >> 3) & 7)) << 4);
    }
    const char* gA = (const char*)(A + (size_t)row0 * K);
    const char* gB = (const char*)(Bt + (size_t)col0 * K);

    auto stage = [&](int kt) {
        const int kb2 = kt * 128;
#pragma unroll
        for (int i = 0; i < 4; ++i)
            load_lds16(gA + (size_t)(offG[i] + kb2), (char*)sA + i * 4096 + wid * 1024);
#pragma unroll
        for (int i = 0; i < NB_B; ++i)
            load_lds16(gB + (size_t)(offG[i] + kb2), (char*)sB + i * 4096 + wid * 1024);
    };

    const int NK = K >> 6;
    stage(0);
    for (int kt = 0; kt < NK; ++kt) {
        __syncthreads();   // drains staged loads
#pragma unroll
        for (int kf = 0; kf < 2; ++kf) {
            const int sl = ((kf * 4 + hg) ^ (lr & 7)) << 4;
            bf16x8 af[AM], bfr[4];
#pragma unroll
            for (int m = 0; m < AM; ++m)
                af[m] = *(const bf16x8*)((const char*)sA + (wrow + m * 16 + lr) * 128 + sl);
#pragma unroll
            for (int n = 0; n < 4; ++n)
                bfr[n] = *(const bf16x8*)((const char*)sB + (wcol + n * 16 + lr) * 128 + sl);
#pragma unroll
            for (int m = 0; m < AM; ++m)
#pragma unroll
                for (int n = 0; n < 4; ++n)
                    acc[m][n] = __builtin_amdgcn_mfma_f32_16x16x32_bf16(af[m], bfr[n], acc[m][n], 0, 0, 0);
        }
        __syncthreads();   // all waves done reading before restage
        if (kt + 1 < NK) stage(kt + 1);
    }

#pragma unroll
    for (int m = 0; m < AM; ++m) {
#pragma unroll
        for (int n = 0; n < 4; ++n) {
            const int colc = col0 + wcol + n * 16 + lr;
            const int rowb = row0 + wrow + m * 16 + hg * 4;
            if constexpr (EPI == 3) {
                if (colc >= 2 * C_) {
                    bf16x4 w;
#pragma unroll
                    for (int j = 0; j < 4; ++j) w[j] = (bf16_t)acc[m][n][j];
                    *(bf16x4*)(vt + (size_t)(colc - 2 * C_) * BT_ + rowb) = w;
                    continue;
                }
            }
#pragma unroll
            for (int j = 0; j < 4; ++j) {
                int row = rowb + j;
                int col = colc;
                float v = acc[m][n][j];
                if constexpr (EPI == 0) {
                    outH[(size_t)row * N + col] = __float2bfloat16(v);
                } else if constexpr (EPI == 2) {
                    float tt = v + bias[col];
                    float ge = 0.5f * tt * (1.0f + erff(tt * 0.70710678118654752f));
                    outH[(size_t)row * N + col] = __float2bfloat16(ge);
                } else if constexpr (EPI == 3) {
                    int typ = col / C_;            // 0=q, 1=k (v handled above)
                    int rr = col - typ * C_;
                    int h = rr >> 6, d = rr & 63;
                    int b = row >> 11, t = row & (T_ - 1);
                    size_t bh = (size_t)b * H_ + h;
                    if (typ == 0) qb[(bh * T_ + t) * D_ + d] = __float2bfloat16(v * scale);
                    else          kb[(bh * T_ + t) * D_ + d] = __float2bfloat16(v);
                } else if constexpr (EPI == 4) {
                    outH[(size_t)row * N + col] =
                        __float2bfloat16(v + bias[col] + residF[(size_t)row * N + col]);
                } else {  // EPI == 5
                    outF[(size_t)row * N + col] =
                        v + bias[col] + __bfloat162float(residH[(size_t)row * N + col]);
                }
            }
        }
    }
}

// ---------------- flash attention (swapped QK^T, defer-max, raw exp2) ----------
// 1D grid 768 (XCD-swizzled). 4 waves x 32 q-rows. q pre-scaled by
// 768^-0.5 * log2(e) -> scores in log2 domain; P = v_exp_f32(st - m) directly.
// Denominator l = P.1 via MFMA ones-fragment (layout matches o; no broadcasts).
__global__ __launch_bounds__(256, 3) void attn_kernel(
    const hbf* __restrict__ qg, const hbf* __restrict__ kg,
    const hbf* __restrict__ vg, hbf* __restrict__ outA)
{
    __shared__ hbf sK0[64 * 64], sK1[64 * 64];   // [s][d], swizzled
    __shared__ hbf sV0[64 * 64], sV1[64 * 64];   // [d][s], swizzled
    __shared__ hbf sP[4 * 32 * 64];              // per wave [q=32][kv=64], swizzled
    const int tid = threadIdx.x, lane = tid & 63, wid = tid >> 6;
    const int lr = lane & 15, hg = lane >> 4;
    const int wg = (blockIdx.x & 7) * 96 + (blockIdx.x >> 3);   // 768/8 = 96
    const int bh = wg >> 4;
    const int b = bh / H_, h = bh - b * H_;
    const int wr0 = (wg & 15) * 128 + wid * 32;
    const hbf* qbh = qg + (size_t)bh * T_ * D_;
    const hbf* kbh = kg + (size_t)bh * T_ * D_;
    const hbf* vbh = vg + (size_t)h * 64 * BT_ + (size_t)b * T_;

    bf16x8 a_q[2][2];
#pragma unroll
    for (int m = 0; m < 2; ++m)
#pragma unroll
        for (int kf = 0; kf < 2; ++kf)
            a_q[m][kf] = *(const bf16x8*)(qbh + (size_t)(wr0 + m * 16 + lr) * D_ + kf * 32 + hg * 8);

    bf16x8 vone;
#pragma unroll
    for (int i = 0; i < 8; ++i) vone[i] = (bf16_t)1.0f;

    f32x4 o[2][4] = {};
    f32x4 lden[2] = {};            // row-sum accumulator, same layout as o
    float mreg[2] = {-3e38f, -3e38f};

    int offK[2], offV[2];
#pragma unroll
    for (int i = 0; i < 2; ++i) {
        int c = tid + i * 256;
        int sw = ((c & 7) ^ ((c >> 3) & 7)) << 4;
        offK[i] = (c >> 3) * 128 + sw;
        offV[i] = (c >> 3) * (BT_ * 2) + sw;
    }
    hbf* sPw = sP + wid * (32 * 64);
    const int sl0 = ((0 * 4 + hg) ^ (lr & 7)) << 4;
    const int sl1 = ((1 * 4 + hg) ^ (lr & 7)) << 4;
    const int bcast = hg * 20;   // source lane hg*16 + (hg*4): for fb[j] add j

    auto stage = [&](int itn, hbf* sKd, hbf* sVd) {
        const char* kp = (const char*)kbh + (size_t)itn * 8192;
        const char* vp = (const char*)vbh + (size_t)itn * 128;
#pragma unroll
        for (int i = 0; i < 2; ++i) {
            load_lds16(kp + offK[i], (char*)sKd + i * 4096 + wid * 1024);
            load_lds16(vp + offV[i], (char*)sVd + i * 4096 + wid * 1024);
        }
    };

    auto tile = [&](const hbf* sKc, const hbf* sVc) {
        f32x4 st[4][2] = {};
        __builtin_amdgcn_s_setprio(1);
#pragma unroll
        for (int kf = 0; kf < 2; ++kf) {
            const int sl = kf ? sl1 : sl0;
#pragma unroll
            for (int n = 0; n < 4; ++n) {
                bf16x8 ak = *(const bf16x8*)((const char*)sKc + (n * 16 + lr) * 128 + sl);
                st[n][0] = __builtin_amdgcn_mfma_f32_16x16x32_bf16(ak, a_q[0][kf], st[n][0], 0, 0, 0);
                st[n][1] = __builtin_amdgcn_mfma_f32_16x16x32_bf16(ak, a_q[1][kf], st[n][1], 0, 0, 0);
            }
        }
        __builtin_amdgcn_s_setprio(0);

#pragma unroll
        for (int m = 0; m < 2; ++m) {
            // balanced max tree (depth 4) over the 16 in-lane values
            f32x4 mx = st[0][m];
            mx[0] = fmaxf(mx[0], st[1][m][0]); mx[1] = fmaxf(mx[1], st[1][m][1]);
            mx[2] = fmaxf(mx[2], st[1][m][2]); mx[3] = fmaxf(mx[3], st[1][m][3]);
            f32x4 my = st[2][m];
            my[0] = fmaxf(my[0], st[3][m][0]); my[1] = fmaxf(my[1], st[3][m][1]);
            my[2] = fmaxf(my[2], st[3][m][2]); my[3] = fmaxf(my[3], st[3][m][3]);
            float t01 = fmaxf(fmaxf(mx[0], my[0]), fmaxf(mx[1], my[1]));
            float t23 = fmaxf(fmaxf(mx[2], my[2]), fmaxf(mx[3], my[3]));
            float t = fmaxf(t01, t23);
            t = fmaxf(t, __shfl_xor(t, 16, 64));
            t = fmaxf(t, __shfl_xor(t, 32, 64));
            if (__any(t - mreg[m] > 11.5415603f)) {   // 8*log2(e): rarely taken
                float nm = fmaxf(mreg[m], t);
                float fac = __builtin_amdgcn_exp2f(mreg[m] - nm);
                mreg[m] = nm;
                float fb[4];
#pragma unroll
                for (int j = 0; j < 4; ++j)
                    fb[j] = __shfl(fac, bcast + j, 64);
#pragma unroll
                for (int j = 0; j < 4; ++j) {
                    lden[m][j] *= fb[j];
#pragma unroll
                    for (int nd = 0; nd < 4; ++nd)
                        o[m][nd][j] *= fb[j];
                }
            }
            const int r = m * 16 + lr;
#pragma unroll
            for (int n = 0; n < 4; ++n) {
                float p0 = __builtin_amdgcn_exp2f(st[n][m][0] - mreg[m]);
                float p1 = __builtin_amdgcn_exp2f(st[n][m][1] - mreg[m]);
                float p2 = __builtin_amdgcn_exp2f(st[n][m][2] - mreg[m]);
                float p3 = __builtin_amdgcn_exp2f(st[n][m][3] - mreg[m]);
                bf16x4 w;
                w[0] = (bf16_t)p0; w[1] = (bf16_t)p1; w[2] = (bf16_t)p2; w[3] = (bf16_t)p3;
                *(bf16x4*)((char*)sPw + r * 128 +
                           (((n * 2 + (hg >> 1)) ^ (r & 7)) << 4) + ((hg & 1) * 8)) = w;
            }
        }

        // PV + MFMA row-sum (l = P.1) — P is wave-private, no block barrier
        __builtin_amdgcn_s_setprio(1);
#pragma unroll
        for (int kf = 0; kf < 2; ++kf) {
            const int sl = kf ? sl1 : sl0;
            bf16x8 ap0 = *(const bf16x8*)((const char*)sPw + lr * 128 + sl);
            bf16x8 ap1 = *(const bf16x8*)((const char*)sPw + (16 + lr) * 128 + sl);
            lden[0] = __builtin_amdgcn_mfma_f32_16x16x32_bf16(ap0, vone, lden[0], 0, 0, 0);
            lden[1] = __builtin_amdgcn_mfma_f32_16x16x32_bf16(ap1, vone, lden[1], 0, 0, 0);
#pragma unroll
            for (int nd = 0; nd < 4; ++nd) {
                bf16x8 bv = *(const bf16x8*)((const char*)sVc + (nd * 16 + lr) * 128 + sl);
                o[0][nd] = __builtin_amdgcn_mfma_f32_16x16x32_bf16(ap0, bv, o[0][nd], 0, 0, 0);
                o[1][nd] = __builtin_amdgcn_mfma_f32_16x16x32_bf16(ap1, bv, o[1][nd], 0, 0, 0);
            }
        }
        __builtin_amdgcn_s_setprio(0);
    };

    const int NT = T_ / 64;   // 32, even
    stage(0, sK0, sV0);
    __syncthreads();
    for (int it = 0; it < NT; it += 2) {
        stage(it + 1, sK1, sV1);
        tile(sK0, sV0);
        __syncthreads();
        if (it + 2 < NT) stage(it + 2, sK0, sV0);
        tile(sK1, sV1);
        __syncthreads();
    }

    // epilogue: l already in o's layout — direct divide, no broadcast
#pragma unroll
    for (int m = 0; m < 2; ++m) {
        f32x4 rinv;
#pragma unroll
        for (int j = 0; j < 4; ++j) rinv[j] = 1.0f / lden[m][j];
#pragma unroll
        for (int nd = 0; nd < 4; ++nd)
#pragma unroll
            for (int j = 0; j < 4; ++j) {
                int row = wr0 + m * 16 + hg * 4 + j;
                int col = nd * 16 + lr;
                outA[((size_t)(b * T_ + row)) * C_ + h * D_ + col] =
                    __float2bfloat16(o[m][nd][j] * rinv[j]);
            }
    }
}

// ---------------- launch ----------------
extern "C" void kernel_launch(void* const* d_in, const int* in_sizes, int n_in,
                              void* d_out, int out_size, void* d_ws, size_t ws_size,
                              hipStream_t stream)
{
    const float* x    = (const float*)d_in[0];
    const float* Wq   = (const float*)d_in[1];
    const float* Wk   = (const float*)d_in[2];
    const float* Wv   = (const float*)d_in[3];
    const float* Wo   = (const float*)d_in[4];
    const float* bo   = (const float*)d_in[5];
    const float* ln1g = (const float*)d_in[6];
    const float* ln1b = (const float*)d_in[7];
    const float* ln2g = (const float*)d_in[8];
    const float* ln2b = (const float*)d_in[9];
    const float* W1   = (const float*)d_in[10];
    const float* b1   = (const float*)d_in[11];
    const float* W2   = (const float*)d_in[12];
    const float* b2   = (const float*)d_in[13];
    float* out = (float*)d_out;
    char* ws = (char*)d_ws;

    hbf*  xn    = (hbf*)(ws + 0);            // 12.58 MB
    hbf*  WqkT  = (hbf*)(ws + 12582912);     // [2304][768] 3.54 MB (q,k,v rows)
    hbf*  qb    = (hbf*)(ws + 16121856);     // 12.58 MB
    hbf*  kb    = (hbf*)(ws + 28704768);     // 12.58 MB
    hbf*  vT    = (hbf*)(ws + 41287680);     // [768][8192] 12.58 MB
    hbf*  h1    = (hbf*)(ws + 0);            // 50.33 MB overlay (dead inputs by MLP)
    hbf*  attnB = (hbf*)(ws + 53870592);     // 12.58 MB
    hbf*  yln   = (hbf*)(ws + 53870592);     // overlays attnB
    hbf*  x2b   = (hbf*)(ws + 66453504);     // 12.58 MB (bf16 residual-1)
    hbf*  WoT   = (hbf*)(ws + 91619328);     // 1.18 MB
    hbf*  W1T   = (hbf*)(ws + 92798976);     // 4.72 MB
    hbf*  W2T   = (hbf*)(ws + 97517568);     // 4.72 MB (end 102,236,160)

    // 768^-0.5 * log2(e): QK^T scores land in log2 domain for raw v_exp_f32
    const float SCALE2 = 0.036084391824351615f * 1.4426950408889634f;

    pack_qkv3<<<dim3(1, 12, 36), 256, 0, stream>>>(Wq, Wk, Wv, WqkT);
    transpose_pack<<<dim3(12, 12, 1), 256, 0, stream>>>(Wo, WoT, 768, 768);
    transpose_pack<<<dim3(48, 12, 1), 256, 0, stream>>>(W1, W1T, 768, 3072);
    transpose_pack<<<dim3(12, 48, 1), 256, 0, stream>>>(W2, W2T, 3072, 768);
    ln_kernel<float><<<8192, 256, 0, stream>>>(x, ln1g, ln1b, xn);
    gemm_kernel<3,128><<<1152, 256, 0, stream>>>(xn, WqkT, nullptr, nullptr, nullptr, nullptr,
        nullptr, 8192, 2304, 768, qb, kb, vT, SCALE2, 18);
    attn_kernel<<<768, 256, 0, stream>>>(qb, kb, vT, attnB);
    gemm_kernel<4,64><<<768, 256, 0, stream>>>(attnB, WoT, nullptr, x2b, bo, x,
        nullptr, 8192, 768, 768, nullptr, nullptr, nullptr, 1.0f, 12);
    ln_kernel<hbf><<<8192, 256, 0, stream>>>(x2b, ln2g, ln2b, yln);
    gemm_kernel<2,128><<<1536, 256, 0, stream>>>(yln, W1T, nullptr, h1, b1, nullptr,
        nullptr, 8192, 3072, 768, nullptr, nullptr, nullptr, 1.0f, 24);
    gemm_kernel<5,64><<<768, 256, 0, stream>>>(h1, W2T, out, nullptr, b2, nullptr,
        x2b, 8192, 768, 3072, nullptr, nullptr, nullptr, 1.0f, 12);
}

// Round 13
// 267.408 us; speedup vs baseline: 1.0754x; 1.0366x over previous
//
#include <hip/hip_runtime.h>
#include <hip/hip_bf16.h>
#include <cstdint>
#include <cmath>

#define B_ 4
#define T_ 2048
#define C_ 768
#define H_ 12
#define D_ 64
#define MLP_ 3072
#define BT_ (B_*T_)

typedef __hip_bfloat16 hbf;
typedef __bf16 bf16_t;
typedef bf16_t bf16x8 __attribute__((ext_vector_type(8)));
typedef bf16_t bf16x4 __attribute__((ext_vector_type(4)));
typedef float f32x4 __attribute__((ext_vector_type(4)));

static __device__ __forceinline__ void load_lds16(const void* g, void* l) {
    __builtin_amdgcn_global_load_lds(
        (const __attribute__((address_space(1))) unsigned int*)g,
        (__attribute__((address_space(3))) unsigned int*)l, 16, 0, 0);
}

// ---------------- LDS-tiled transpose: f32 [R][S] -> bf16 [S][R] ----------------
__global__ __launch_bounds__(256) void transpose_pack(
    const float* __restrict__ src, hbf* __restrict__ dst, int R, int S)
{
    __shared__ float tl[64 * 65];
    src += (size_t)blockIdx.z * R * S;
    dst += (size_t)blockIdx.z * R * S;
    const int r0 = blockIdx.y * 64, s0 = blockIdx.x * 64;
    const int c = threadIdx.x & 63, q = threadIdx.x >> 6;
#pragma unroll
    for (int j = 0; j < 16; ++j) {
        int r = q + j * 4;
        tl[r * 65 + c] = src[(size_t)(r0 + r) * S + s0 + c];
    }
    __syncthreads();
#pragma unroll
    for (int j = 0; j < 16; ++j) {
        int s = q + j * 4;
        dst[(size_t)(s0 + s) * R + r0 + c] = __float2bfloat16(tl[c * 65 + s]);
    }
}

// Combined q/k/v weight pack: 36 z-slices of [768][64] -> rows of WqkT [2304][768].
__global__ __launch_bounds__(256) void pack_qkv3(
    const float* __restrict__ Wq, const float* __restrict__ Wk,
    const float* __restrict__ Wv, hbf* __restrict__ WqkT)
{
    __shared__ float tl[64 * 65];
    const int z = blockIdx.z;
    const int mtx = z / 12, head = z - mtx * 12;
    const float* src = (mtx == 0 ? Wq : mtx == 1 ? Wk : Wv) + (size_t)head * 49152;
    hbf* dst = WqkT + (size_t)z * 49152;
    const int r0 = blockIdx.y * 64;
    const int c = threadIdx.x & 63, q = threadIdx.x >> 6;
#pragma unroll
    for (int j = 0; j < 16; ++j) {
        int r = q + j * 4;
        tl[r * 65 + c] = src[(size_t)(r0 + r) * 64 + c];
    }
    __syncthreads();
#pragma unroll
    for (int j = 0; j < 16; ++j) {
        int s = q + j * 4;
        dst[(size_t)s * 768 + r0 + c] = __float2bfloat16(tl[c * 65 + s]);
    }
}

// ---------------- layernorm (row = 768), vectorized: 192 thr x 4 elems --------
template<typename TI>
__global__ __launch_bounds__(192) void ln_kernel(
    const TI* __restrict__ x, const float* __restrict__ g,
    const float* __restrict__ bb, hbf* __restrict__ out)
{
    __shared__ float red[6];
    const int row = blockIdx.x;
    const int t = threadIdx.x;
    float v[4];
    if constexpr (__is_same(TI, float)) {
        const float4 xv = *(const float4*)(x + (size_t)row * C_ + t * 4);
        v[0] = xv.x; v[1] = xv.y; v[2] = xv.z; v[3] = xv.w;
    } else {
        bf16x4 xv = *(const bf16x4*)((const bf16_t*)x + (size_t)row * C_ + t * 4);
#pragma unroll
        for (int k = 0; k < 4; ++k) v[k] = (float)xv[k];
    }
    float s = 0.0f, s2 = 0.0f;
#pragma unroll
    for (int k = 0; k < 4; ++k) { s += v[k]; s2 += v[k] * v[k]; }
#pragma unroll
    for (int m = 1; m < 64; m <<= 1) {
        s  += __shfl_xor(s,  m, 64);
        s2 += __shfl_xor(s2, m, 64);
    }
    if ((t & 63) == 0) { red[t >> 6] = s; red[3 + (t >> 6)] = s2; }
    __syncthreads();
    float S  = red[0] + red[1] + red[2];
    float S2 = red[3] + red[4] + red[5];
    float mu  = S * (1.0f / C_);
    float var = S2 * (1.0f / C_) - mu * mu;
    float inv = rsqrtf(var + 1e-6f);
    const float4 gv = *(const float4*)(g  + t * 4);
    const float4 bv = *(const float4*)(bb + t * 4);
    bf16x4 o4;
    o4[0] = (bf16_t)((v[0] - mu) * inv * gv.x + bv.x);
    o4[1] = (bf16_t)((v[1] - mu) * inv * gv.y + bv.y);
    o4[2] = (bf16_t)((v[2] - mu) * inv * gv.z + bv.z);
    o4[3] = (bf16_t)((v[3] - mu) * inv * gv.w + bv.w);
    *(bf16x4*)((bf16_t*)out + (size_t)row * C_ + t * 4) = o4;
}

// ---------------- GEMM: C[M,N] = A[M,K](bf16) * Bt[N,K](bf16)^T ----------------
// BK=64, tile 128xTN (TN=128 or 64), XOR-swizzled LDS, SINGLE buffer,
// 2-barrier loop, 1D grid + XCD swizzle. TN=64 runs 4 blocks/CU.
// (r10-verified; explicit dbuf re-tested r11 and regressed — do not re-add.)
template<int EPI, int TN>
__global__ __launch_bounds__(256, (TN == 64) ? 4 : 3) void gemm_kernel(
    const hbf* __restrict__ A, const hbf* __restrict__ Bt,
    float* __restrict__ outF, hbf* __restrict__ outH,
    const float* __restrict__ bias, const float* __restrict__ residF,
    const hbf* __restrict__ residH,
    int M, int N, int K,
    hbf* __restrict__ qb, hbf* __restrict__ kb, hbf* __restrict__ vt,
    float scale, int gx)
{
    constexpr int AM = (TN == 128) ? 4 : 2;     // m-frags per wave
    constexpr int NB_B = (TN == 128) ? 4 : 2;   // B staging iters
    __shared__ hbf sA[128 * 64];
    __shared__ hbf sB[TN * 64];
    const int tid = threadIdx.x;
    const int lane = tid & 63;
    const int wid = tid >> 6;
    const int lr = lane & 15, hg = lane >> 4;
    const int bid = blockIdx.x, nwg = gridDim.x;
    const int wg = (bid & 7) * (nwg >> 3) + (bid >> 3);
    const int bx = wg % gx, by = wg / gx;
    const int row0 = by * 128;
    const int col0 = bx * TN;
    const int wrow = (TN == 128) ? (wid >> 1) * 64 : wid * 32;
    const int wcol = (TN == 128) ? (wid & 1) * 64 : 0;

    f32x4 acc[AM][4] = {};

    int offG[4];
    const int Kb = K * 2;
#pragma unroll
    for (int i = 0; i < 4; ++i) {
        int c = tid + i * 256;
        offG[i] = (c >> 3) * Kb + (((c & 7) ^ ((c >> 3) & 7)) << 4);
    }
    const char* gA = (const char*)(A + (size_t)row0 * K);
    const char* gB = (const char*)(Bt + (size_t)col0 * K);

    auto stage = [&](int kt) {
        const int kb2 = kt * 128;
#pragma unroll
        for (int i = 0; i < 4; ++i)
            load_lds16(gA + (size_t)(offG[i] + kb2), (char*)sA + i * 4096 + wid * 1024);
#pragma unroll
        for (int i = 0; i < NB_B; ++i)
            load_lds16(gB + (size_t)(offG[i] + kb2), (char*)sB + i * 4096 + wid * 1024);
    };

    const int NK = K >> 6;
    stage(0);
    for (int kt = 0; kt < NK; ++kt) {
        __syncthreads();   // drains staged loads
#pragma unroll
        for (int kf = 0; kf < 2; ++kf) {
            const int sl = ((kf * 4 + hg) ^ (lr & 7)) << 4;
            bf16x8 af[AM], bfr[4];
#pragma unroll
            for (int m = 0; m < AM; ++m)
                af[m] = *(const bf16x8*)((const char*)sA + (wrow + m * 16 + lr) * 128 + sl);
#pragma unroll
            for (int n = 0; n < 4; ++n)
                bfr[n] = *(const bf16x8*)((const char*)sB + (wcol + n * 16 + lr) * 128 + sl);
#pragma unroll
            for (int m = 0; m < AM; ++m)
#pragma unroll
                for (int n = 0; n < 4; ++n)
                    acc[m][n] = __builtin_amdgcn_mfma_f32_16x16x32_bf16(af[m], bfr[n], acc[m][n], 0, 0, 0);
        }
        __syncthreads();   // all waves done reading before restage
        if (kt + 1 < NK) stage(kt + 1);
    }

#pragma unroll
    for (int m = 0; m < AM; ++m) {
#pragma unroll
        for (int n = 0; n < 4; ++n) {
            const int colc = col0 + wcol + n * 16 + lr;
            const int rowb = row0 + wrow + m * 16 + hg * 4;
            if constexpr (EPI == 3) {
                if (colc >= 2 * C_) {
                    bf16x4 w;
#pragma unroll
                    for (int j = 0; j < 4; ++j) w[j] = (bf16_t)acc[m][n][j];
                    *(bf16x4*)(vt + (size_t)(colc - 2 * C_) * BT_ + rowb) = w;
                    continue;
                }
            }
#pragma unroll
            for (int j = 0; j < 4; ++j) {
                int row = rowb + j;
                int col = colc;
                float v = acc[m][n][j];
                if constexpr (EPI == 0) {
                    outH[(size_t)row * N + col] = __float2bfloat16(v);
                } else if constexpr (EPI == 2) {
                    // tanh-form GELU: ge = t*e/(e+1), e = exp2(2.3021142*t + 0.10294234*t^3)
                    float tt = v + bias[col];
                    float t3 = tt * tt * tt;
                    float z = fminf(fmaf(t3, 0.1029423372f, 2.3021141876f * tt), 126.0f);
                    float e = __builtin_amdgcn_exp2f(z);
                    float ge = tt * e * __builtin_amdgcn_rcpf(e + 1.0f);
                    outH[(size_t)row * N + col] = __float2bfloat16(ge);
                } else if constexpr (EPI == 3) {
                    int typ = col / C_;            // 0=q, 1=k (v handled above)
                    int rr = col - typ * C_;
                    int h = rr >> 6, d = rr & 63;
                    int b = row >> 11, t = row & (T_ - 1);
                    size_t bh = (size_t)b * H_ + h;
                    if (typ == 0) qb[(bh * T_ + t) * D_ + d] = __float2bfloat16(v * scale);
                    else          kb[(bh * T_ + t) * D_ + d] = __float2bfloat16(v);
                } else if constexpr (EPI == 4) {
                    outH[(size_t)row * N + col] =
                        __float2bfloat16(v + bias[col] + residF[(size_t)row * N + col]);
                } else {  // EPI == 5
                    outF[(size_t)row * N + col] =
                        v + bias[col] + __bfloat162float(residH[(size_t)row * N + col]);
                }
            }
        }
    }
}

// ---------------- flash attention (swapped QK^T, defer-max, raw exp2) ----------
// 1D grid 768 (XCD-swizzled). 4 waves x 32 q-rows. q pre-scaled by
// 768^-0.5 * log2(e). Cross-lane max: permlane32_swap (VALU) + one shfl16,
// both m-blocks' chains interleaved so their latencies overlap.
// Denominator l = P.1 via MFMA ones-fragment (layout matches o; no broadcasts).
__global__ __launch_bounds__(256, 3) void attn_kernel(
    const hbf* __restrict__ qg, const hbf* __restrict__ kg,
    const hbf* __restrict__ vg, hbf* __restrict__ outA)
{
    __shared__ hbf sK0[64 * 64], sK1[64 * 64];   // [s][d], swizzled
    __shared__ hbf sV0[64 * 64], sV1[64 * 64];   // [d][s], swizzled
    __shared__ hbf sP[4 * 32 * 64];              // per wave [q=32][kv=64], swizzled
    const int tid = threadIdx.x, lane = tid & 63, wid = tid >> 6;
    const int lr = lane & 15, hg = lane >> 4;
    const int wg = (blockIdx.x & 7) * 96 + (blockIdx.x >> 3);   // 768/8 = 96
    const int bh = wg >> 4;
    const int b = bh / H_, h = bh - b * H_;
    const int wr0 = (wg & 15) * 128 + wid * 32;
    const hbf* qbh = qg + (size_t)bh * T_ * D_;
    const hbf* kbh = kg + (size_t)bh * T_ * D_;
    const hbf* vbh = vg + (size_t)h * 64 * BT_ + (size_t)b * T_;

    bf16x8 a_q[2][2];
#pragma unroll
    for (int m = 0; m < 2; ++m)
#pragma unroll
        for (int kf = 0; kf < 2; ++kf)
            a_q[m][kf] = *(const bf16x8*)(qbh + (size_t)(wr0 + m * 16 + lr) * D_ + kf * 32 + hg * 8);

    bf16x8 vone;
#pragma unroll
    for (int i = 0; i < 8; ++i) vone[i] = (bf16_t)1.0f;

    f32x4 o[2][4] = {};
    f32x4 lden[2] = {};            // row-sum accumulator, same layout as o
    float mreg[2] = {-3e38f, -3e38f};

    int offK[2], offV[2];
#pragma unroll
    for (int i = 0; i < 2; ++i) {
        int c = tid + i * 256;
        int sw = ((c & 7) ^ ((c >> 3) & 7)) << 4;
        offK[i] = (c >> 3) * 128 + sw;
        offV[i] = (c >> 3) * (BT_ * 2) + sw;
    }
    hbf* sPw = sP + wid * (32 * 64);
    const int sl0 = ((0 * 4 + hg) ^ (lr & 7)) << 4;
    const int sl1 = ((1 * 4 + hg) ^ (lr & 7)) << 4;
    const int bcast = hg * 20;   // source lane hg*16 + (hg*4): for fb[j] add j

    auto stage = [&](int itn, hbf* sKd, hbf* sVd) {
        const char* kp = (const char*)kbh + (size_t)itn * 8192;
        const char* vp = (const char*)vbh + (size_t)itn * 128;
#pragma unroll
        for (int i = 0; i < 2; ++i) {
            load_lds16(kp + offK[i], (char*)sKd + i * 4096 + wid * 1024);
            load_lds16(vp + offV[i], (char*)sVd + i * 4096 + wid * 1024);
        }
    };

    auto tile = [&](const hbf* sKc, const hbf* sVc) {
        f32x4 st[4][2] = {};
        __builtin_amdgcn_s_setprio(1);
#pragma unroll
        for (int kf = 0; kf < 2; ++kf) {
            const int sl = kf ? sl1 : sl0;
#pragma unroll
            for (int n = 0; n < 4; ++n) {
                bf16x8 ak = *(const bf16x8*)((const char*)sKc + (n * 16 + lr) * 128 + sl);
                st[n][0] = __builtin_amdgcn_mfma_f32_16x16x32_bf16(ak, a_q[0][kf], st[n][0], 0, 0, 0);
                st[n][1] = __builtin_amdgcn_mfma_f32_16x16x32_bf16(ak, a_q[1][kf], st[n][1], 0, 0, 0);
            }
        }
        __builtin_amdgcn_s_setprio(0);

        // balanced in-lane max trees for BOTH m-blocks (independent chains)
        float tm[2];
#pragma unroll
        for (int m = 0; m < 2; ++m) {
            f32x4 mx = st[0][m];
            mx[0] = fmaxf(mx[0], st[1][m][0]); mx[1] = fmaxf(mx[1], st[1][m][1]);
            mx[2] = fmaxf(mx[2], st[1][m][2]); mx[3] = fmaxf(mx[3], st[1][m][3]);
            f32x4 my = st[2][m];
            my[0] = fmaxf(my[0], st[3][m][0]); my[1] = fmaxf(my[1], st[3][m][1]);
            my[2] = fmaxf(my[2], st[3][m][2]); my[3] = fmaxf(my[3], st[3][m][3]);
            float t01 = fmaxf(fmaxf(mx[0], my[0]), fmaxf(mx[1], my[1]));
            float t23 = fmaxf(fmaxf(mx[2], my[2]), fmaxf(mx[3], my[3]));
            tm[m] = fmaxf(t01, t23);
        }
        // cross-lane: ±32 via permlane32_swap (VALU pipe), ±16 via one shfl;
        // both chains issued back-to-back so latencies overlap.
        {
            float a0 = tm[0], b0 = tm[0], a1 = tm[1], b1 = tm[1];
            asm volatile("v_permlane32_swap_b32 %0, %1" : "+v"(a0), "+v"(b0));
            asm volatile("v_permlane32_swap_b32 %0, %1" : "+v"(a1), "+v"(b1));
            a0 = fmaxf(a0, b0);
            a1 = fmaxf(a1, b1);
            float s0 = __shfl_xor(a0, 16, 64);
            float s1 = __shfl_xor(a1, 16, 64);
            tm[0] = fmaxf(a0, s0);
            tm[1] = fmaxf(a1, s1);
        }

#pragma unroll
        for (int m = 0; m < 2; ++m) {
            const float t = tm[m];
            if (__any(t - mreg[m] > 11.5415603f)) {   // 8*log2(e): rarely taken
                float nm = fmaxf(mreg[m], t);
                float fac = __builtin_amdgcn_exp2f(mreg[m] - nm);
                mreg[m] = nm;
                float fb[4];
#pragma unroll
                for (int j = 0; j < 4; ++j)
                    fb[j] = __shfl(fac, bcast + j, 64);
#pragma unroll
                for (int j = 0; j < 4; ++j) {
                    lden[m][j] *= fb[j];
#pragma unroll
                    for (int nd = 0; nd < 4; ++nd)
                        o[m][nd][j] *= fb[j];
                }
            }
            const int r = m * 16 + lr;
#pragma unroll
            for (int n = 0; n < 4; ++n) {
                float p0 = __builtin_amdgcn_exp2f(st[n][m][0] - mreg[m]);
                float p1 = __builtin_amdgcn_exp2f(st[n][m][1] - mreg[m]);
                float p2 = __builtin_amdgcn_exp2f(st[n][m][2] - mreg[m]);
                float p3 = __builtin_amdgcn_exp2f(st[n][m][3] - mreg[m]);
                bf16x4 w;
                w[0] = (bf16_t)p0; w[1] = (bf16_t)p1; w[2] = (bf16_t)p2; w[3] = (bf16_t)p3;
                *(bf16x4*)((char*)sPw + r * 128 +
                           (((n * 2 + (hg >> 1)) ^ (r & 7)) << 4) + ((hg & 1) * 8)) = w;
            }
        }

        // PV + MFMA row-sum (l = P.1) — P is wave-private, no block barrier
        __builtin_amdgcn_s_setprio(1);
#pragma unroll
        for (int kf = 0; kf < 2; ++kf) {
            const int sl = kf ? sl1 : sl0;
            bf16x8 ap0 = *(const bf16x8*)((const char*)sPw + lr * 128 + sl);
            bf16x8 ap1 = *(const bf16x8*)((const char*)sPw + (16 + lr) * 128 + sl);
            lden[0] = __builtin_amdgcn_mfma_f32_16x16x32_bf16(ap0, vone, lden[0], 0, 0, 0);
            lden[1] = __builtin_amdgcn_mfma_f32_16x16x32_bf16(ap1, vone, lden[1], 0, 0, 0);
#pragma unroll
            for (int nd = 0; nd < 4; ++nd) {
                bf16x8 bv = *(const bf16x8*)((const char*)sVc + (nd * 16 + lr) * 128 + sl);
                o[0][nd] = __builtin_amdgcn_mfma_f32_16x16x32_bf16(ap0, bv, o[0][nd], 0, 0, 0);
                o[1][nd] = __builtin_amdgcn_mfma_f32_16x16x32_bf16(ap1, bv, o[1][nd], 0, 0, 0);
            }
        }
        __builtin_amdgcn_s_setprio(0);
    };

    const int NT = T_ / 64;   // 32, even
    stage(0, sK0, sV0);
    __syncthreads();
    for (int it = 0; it < NT; it += 2) {
        stage(it + 1, sK1, sV1);
        tile(sK0, sV0);
        __syncthreads();
        if (it + 2 < NT) stage(it + 2, sK0, sV0);
        tile(sK1, sV1);
        __syncthreads();
    }

    // epilogue: l already in o's layout — direct divide, no broadcast
#pragma unroll
    for (int m = 0; m < 2; ++m) {
        f32x4 rinv;
#pragma unroll
        for (int j = 0; j < 4; ++j) rinv[j] = 1.0f / lden[m][j];
#pragma unroll
        for (int nd = 0; nd < 4; ++nd)
#pragma unroll
            for (int j = 0; j < 4; ++j) {
                int row = wr0 + m * 16 + hg * 4 + j;
                int col = nd * 16 + lr;
                outA[((size_t)(b * T_ + row)) * C_ + h * D_ + col] =
                    __float2bfloat16(o[m][nd][j] * rinv[j]);
            }
    }
}

// ---------------- launch ----------------
extern "C" void kernel_launch(void* const* d_in, const int* in_sizes, int n_in,
                              void* d_out, int out_size, void* d_ws, size_t ws_size,
                              hipStream_t stream)
{
    const float* x    = (const float*)d_in[0];
    const float* Wq   = (const float*)d_in[1];
    const float* Wk   = (const float*)d_in[2];
    const float* Wv   = (const float*)d_in[3];
    const float* Wo   = (const float*)d_in[4];
    const float* bo   = (const float*)d_in[5];
    const float* ln1g = (const float*)d_in[6];
    const float* ln1b = (const float*)d_in[7];
    const float* ln2g = (const float*)d_in[8];
    const float* ln2b = (const float*)d_in[9];
    const float* W1   = (const float*)d_in[10];
    const float* b1   = (const float*)d_in[11];
    const float* W2   = (const float*)d_in[12];
    const float* b2   = (const float*)d_in[13];
    float* out = (float*)d_out;
    char* ws = (char*)d_ws;

    hbf*  xn    = (hbf*)(ws + 0);            // 12.58 MB
    hbf*  WqkT  = (hbf*)(ws + 12582912);     // [2304][768] 3.54 MB (q,k,v rows)
    hbf*  qb    = (hbf*)(ws + 16121856);     // 12.58 MB
    hbf*  kb    = (hbf*)(ws + 28704768);     // 12.58 MB
    hbf*  vT    = (hbf*)(ws + 41287680);     // [768][8192] 12.58 MB
    hbf*  h1    = (hbf*)(ws + 0);            // 50.33 MB overlay (dead inputs by MLP)
    hbf*  attnB = (hbf*)(ws + 53870592);     // 12.58 MB
    hbf*  yln   = (hbf*)(ws + 53870592);     // overlays attnB
    hbf*  x2b   = (hbf*)(ws + 66453504);     // 12.58 MB (bf16 residual-1)
    hbf*  WoT   = (hbf*)(ws + 91619328);     // 1.18 MB
    hbf*  W1T   = (hbf*)(ws + 92798976);     // 4.72 MB
    hbf*  W2T   = (hbf*)(ws + 97517568);     // 4.72 MB (end 102,236,160)

    // 768^-0.5 * log2(e): QK^T scores land in log2 domain for raw v_exp_f32
    const float SCALE2 = 0.036084391824351615f * 1.4426950408889634f;

    pack_qkv3<<<dim3(1, 12, 36), 256, 0, stream>>>(Wq, Wk, Wv, WqkT);
    transpose_pack<<<dim3(12, 12, 1), 256, 0, stream>>>(Wo, WoT, 768, 768);
    transpose_pack<<<dim3(48, 12, 1), 256, 0, stream>>>(W1, W1T, 768, 3072);
    transpose_pack<<<dim3(12, 48, 1), 256, 0, stream>>>(W2, W2T, 3072, 768);
    ln_kernel<float><<<8192, 192, 0, stream>>>(x, ln1g, ln1b, xn);
    gemm_kernel<3,128><<<1152, 256, 0, stream>>>(xn, WqkT, nullptr, nullptr, nullptr, nullptr,
        nullptr, 8192, 2304, 768, qb, kb, vT, SCALE2, 18);
    attn_kernel<<<768, 256, 0, stream>>>(qb, kb, vT, attnB);
    gemm_kernel<4,64><<<768, 256, 0, stream>>>(attnB, WoT, nullptr, x2b, bo, x,
        nullptr, 8192, 768, 768, nullptr, nullptr, nullptr, 1.0f, 12);
    ln_kernel<hbf><<<8192, 192, 0, stream>>>(x2b, ln2g, ln2b, yln);
    gemm_kernel<2,128><<<1536, 256, 0, stream>>>(yln, W1T, nullptr, h1, b1, nullptr,
        nullptr, 8192, 3072, 768, nullptr, nullptr, nullptr, 1.0f, 24);
    gemm_kernel<5,64><<<768, 256, 0, stream>>>(h1, W2T, out, nullptr, b2, nullptr,
        x2b, 8192, 768, 3072, nullptr, nullptr, nullptr, 1.0f, 12);
}

// Round 14
// 258.779 us; speedup vs baseline: 1.1112x; 1.0333x over previous
//
#include <hip/hip_runtime.h>
#include <hip/hip_bf16.h>
#include <cstdint>
#include <cmath>

#define B_ 4
#define T_ 2048
#define C_ 768
#define H_ 12
#define D_ 64
#define MLP_ 3072
#define BT_ (B_*T_)

typedef __hip_bfloat16 hbf;
typedef __bf16 bf16_t;
typedef bf16_t bf16x8 __attribute__((ext_vector_type(8)));
typedef bf16_t bf16x4 __attribute__((ext_vector_type(4)));
typedef float f32x4 __attribute__((ext_vector_type(4)));

static __device__ __forceinline__ void load_lds16(const void* g, void* l) {
    __builtin_amdgcn_global_load_lds(
        (const __attribute__((address_space(1))) unsigned int*)g,
        (__attribute__((address_space(3))) unsigned int*)l, 16, 0, 0);
}

// ---------------- unified weight pack: one launch, 1728 tile-transposes -------
// Each block: 64x64 f32 tile of src [R][S] -> bf16 dst [S][R].
// blk [0,432): qkv slices (z=blk/12: mtx*12+head; y=blk%12), R=768,S=64
// blk [432,576): Wo 12x12      blk [576,1152): W1 48x12    blk [1152,1728): W2 12x48
__global__ __launch_bounds__(256) void pack_all(
    const float* __restrict__ Wq, const float* __restrict__ Wk,
    const float* __restrict__ Wv, const float* __restrict__ Wo,
    const float* __restrict__ W1, const float* __restrict__ W2,
    hbf* __restrict__ WqkT, hbf* __restrict__ WoT,
    hbf* __restrict__ W1T, hbf* __restrict__ W2T)
{
    __shared__ float tl[64 * 65];
    const int blk = blockIdx.x;
    const float* src; hbf* dst; int R, S, r0, s0;
    if (blk < 432) {
        const int z = blk / 12, y = blk - z * 12;
        const int mtx = z / 12, head = z - mtx * 12;
        src = (mtx == 0 ? Wq : mtx == 1 ? Wk : Wv) + (size_t)head * 49152;
        dst = WqkT + (size_t)z * 49152;
        R = 768; S = 64; r0 = y * 64; s0 = 0;
    } else if (blk < 576) {
        const int l = blk - 432;
        src = Wo; dst = WoT; R = 768; S = 768;
        r0 = (l / 12) * 64; s0 = (l % 12) * 64;
    } else if (blk < 1152) {
        const int l = blk - 576;
        src = W1; dst = W1T; R = 768; S = 3072;
        r0 = (l / 48) * 64; s0 = (l % 48) * 64;
    } else {
        const int l = blk - 1152;
        src = W2; dst = W2T; R = 3072; S = 768;
        r0 = (l / 12) * 64; s0 = (l % 12) * 64;
    }
    const int c = threadIdx.x & 63, q = threadIdx.x >> 6;
#pragma unroll
    for (int j = 0; j < 16; ++j) {
        int r = q + j * 4;
        tl[r * 65 + c] = src[(size_t)(r0 + r) * S + s0 + c];
    }
    __syncthreads();
#pragma unroll
    for (int j = 0; j < 16; ++j) {
        int s = q + j * 4;
        dst[(size_t)(s0 + s) * R + r0 + c] = __float2bfloat16(tl[c * 65 + s]);
    }
}

// ---------------- layernorm (row = 768), vectorized: 192 thr x 4 elems --------
template<typename TI>
__global__ __launch_bounds__(192) void ln_kernel(
    const TI* __restrict__ x, const float* __restrict__ g,
    const float* __restrict__ bb, hbf* __restrict__ out)
{
    __shared__ float red[6];
    const int row = blockIdx.x;
    const int t = threadIdx.x;
    float v[4];
    if constexpr (__is_same(TI, float)) {
        const float4 xv = *(const float4*)(x + (size_t)row * C_ + t * 4);
        v[0] = xv.x; v[1] = xv.y; v[2] = xv.z; v[3] = xv.w;
    } else {
        bf16x4 xv = *(const bf16x4*)((const bf16_t*)x + (size_t)row * C_ + t * 4);
#pragma unroll
        for (int k = 0; k < 4; ++k) v[k] = (float)xv[k];
    }
    float s = 0.0f, s2 = 0.0f;
#pragma unroll
    for (int k = 0; k < 4; ++k) { s += v[k]; s2 += v[k] * v[k]; }
#pragma unroll
    for (int m = 1; m < 64; m <<= 1) {
        s  += __shfl_xor(s,  m, 64);
        s2 += __shfl_xor(s2, m, 64);
    }
    if ((t & 63) == 0) { red[t >> 6] = s; red[3 + (t >> 6)] = s2; }
    __syncthreads();
    float S  = red[0] + red[1] + red[2];
    float S2 = red[3] + red[4] + red[5];
    float mu  = S * (1.0f / C_);
    float var = S2 * (1.0f / C_) - mu * mu;
    float inv = rsqrtf(var + 1e-6f);
    const float4 gv = *(const float4*)(g  + t * 4);
    const float4 bv = *(const float4*)(bb + t * 4);
    bf16x4 o4;
    o4[0] = (bf16_t)((v[0] - mu) * inv * gv.x + bv.x);
    o4[1] = (bf16_t)((v[1] - mu) * inv * gv.y + bv.y);
    o4[2] = (bf16_t)((v[2] - mu) * inv * gv.z + bv.z);
    o4[3] = (bf16_t)((v[3] - mu) * inv * gv.w + bv.w);
    *(bf16x4*)((bf16_t*)out + (size_t)row * C_ + t * 4) = o4;
}

// ---------------- GEMM: C[M,N] = A[M,K](bf16) * Bt[N,K](bf16)^T ----------------
// BK=64, tile 128xTN (TN=128 or 64), XOR-swizzled LDS, SINGLE buffer,
// 2-barrier loop, 1D grid + XCD swizzle. Both variants 4 blocks/CU
// (TN=128 main loop ~121 VGPR <= 128 cap; r11 dbuf regression locked out).
template<int EPI, int TN>
__global__ __launch_bounds__(256, 4) void gemm_kernel(
    const hbf* __restrict__ A, const hbf* __restrict__ Bt,
    float* __restrict__ outF, hbf* __restrict__ outH,
    const float* __restrict__ bias, const float* __restrict__ residF,
    const hbf* __restrict__ residH,
    int M, int N, int K,
    hbf* __restrict__ qb, hbf* __restrict__ kb, hbf* __restrict__ vt,
    float scale, int gx)
{
    constexpr int AM = (TN == 128) ? 4 : 2;     // m-frags per wave
    constexpr int NB_B = (TN == 128) ? 4 : 2;   // B staging iters
    __shared__ hbf sA[128 * 64];
    __shared__ hbf sB[TN * 64];
    const int tid = threadIdx.x;
    const int lane = tid & 63;
    const int wid = tid >> 6;
    const int lr = lane & 15, hg = lane >> 4;
    const int bid = blockIdx.x, nwg = gridDim.x;
    const int wg = (bid & 7) * (nwg >> 3) + (bid >> 3);
    const int bx = wg % gx, by = wg / gx;
    const int row0 = by * 128;
    const int col0 = bx * TN;
    const int wrow = (TN == 128) ? (wid >> 1) * 64 : wid * 32;
    const int wcol = (TN == 128) ? (wid & 1) * 64 : 0;

    f32x4 acc[AM][4] = {};

    int offG[4];
    const int Kb = K * 2;
#pragma unroll
    for (int i = 0; i < 4; ++i) {
        int c = tid + i * 256;
        offG[i] = (c >> 3) * Kb + (((c & 7) ^ ((c >> 3) & 7)) << 4);
    }
    const char* gA = (const char*)(A + (size_t)row0 * K);
    const char* gB = (const char*)(Bt + (size_t)col0 * K);

    auto stage = [&](int kt) {
        const int kb2 = kt * 128;
#pragma unroll
        for (int i = 0; i < 4; ++i)
            load_lds16(gA + (size_t)(offG[i] + kb2), (char*)sA + i * 4096 + wid * 1024);
#pragma unroll
        for (int i = 0; i < NB_B; ++i)
            load_lds16(gB + (size_t)(offG[i] + kb2), (char*)sB + i * 4096 + wid * 1024);
    };

    const int NK = K >> 6;
    stage(0);
    for (int kt = 0; kt < NK; ++kt) {
        __syncthreads();   // drains staged loads
#pragma unroll
        for (int kf = 0; kf < 2; ++kf) {
            const int sl = ((kf * 4 + hg) ^ (lr & 7)) << 4;
            bf16x8 af[AM], bfr[4];
#pragma unroll
            for (int m = 0; m < AM; ++m)
                af[m] = *(const bf16x8*)((const char*)sA + (wrow + m * 16 + lr) * 128 + sl);
#pragma unroll
            for (int n = 0; n < 4; ++n)
                bfr[n] = *(const bf16x8*)((const char*)sB + (wcol + n * 16 + lr) * 128 + sl);
#pragma unroll
            for (int m = 0; m < AM; ++m)
#pragma unroll
                for (int n = 0; n < 4; ++n)
                    acc[m][n] = __builtin_amdgcn_mfma_f32_16x16x32_bf16(af[m], bfr[n], acc[m][n], 0, 0, 0);
        }
        __syncthreads();   // all waves done reading before restage
        if (kt + 1 < NK) stage(kt + 1);
    }

#pragma unroll
    for (int m = 0; m < AM; ++m) {
#pragma unroll
        for (int n = 0; n < 4; ++n) {
            const int colc = col0 + wcol + n * 16 + lr;
            const int rowb = row0 + wrow + m * 16 + hg * 4;
            if constexpr (EPI == 3) {
                if (colc >= 2 * C_) {
                    bf16x4 w;
#pragma unroll
                    for (int j = 0; j < 4; ++j) w[j] = (bf16_t)acc[m][n][j];
                    *(bf16x4*)(vt + (size_t)(colc - 2 * C_) * BT_ + rowb) = w;
                    continue;
                }
            }
#pragma unroll
            for (int j = 0; j < 4; ++j) {
                int row = rowb + j;
                int col = colc;
                float v = acc[m][n][j];
                if constexpr (EPI == 0) {
                    outH[(size_t)row * N + col] = __float2bfloat16(v);
                } else if constexpr (EPI == 2) {
                    // tanh-form GELU: ge = t*e/(e+1), e = exp2(2.3021142*t + 0.10294234*t^3)
                    float tt = v + bias[col];
                    float t3 = tt * tt * tt;
                    float z = fminf(fmaf(t3, 0.1029423372f, 2.3021141876f * tt), 126.0f);
                    float e = __builtin_amdgcn_exp2f(z);
                    float ge = tt * e * __builtin_amdgcn_rcpf(e + 1.0f);
                    outH[(size_t)row * N + col] = __float2bfloat16(ge);
                } else if constexpr (EPI == 3) {
                    int typ = col / C_;            // 0=q, 1=k (v handled above)
                    int rr = col - typ * C_;
                    int h = rr >> 6, d = rr & 63;
                    int b = row >> 11, t = row & (T_ - 1);
                    size_t bh = (size_t)b * H_ + h;
                    if (typ == 0) qb[(bh * T_ + t) * D_ + d] = __float2bfloat16(v * scale);
                    else          kb[(bh * T_ + t) * D_ + d] = __float2bfloat16(v);
                } else if constexpr (EPI == 4) {
                    outH[(size_t)row * N + col] =
                        __float2bfloat16(v + bias[col] + residF[(size_t)row * N + col]);
                } else {  // EPI == 5
                    outF[(size_t)row * N + col] =
                        v + bias[col] + __bfloat162float(residH[(size_t)row * N + col]);
                }
            }
        }
    }
}

// ---------------- flash attention (swapped QK^T, defer-max, raw exp2) ----------
// 1D grid 768 (XCD-swizzled). 4 waves x 32 q-rows. q pre-scaled by
// 768^-0.5 * log2(e). Cross-lane max: permlane32_swap (VALU) + one shfl16,
// both m-blocks' chains interleaved so their latencies overlap.
// Denominator l = P.1 via MFMA ones-fragment (layout matches o; no broadcasts).
__global__ __launch_bounds__(256, 3) void attn_kernel(
    const hbf* __restrict__ qg, const hbf* __restrict__ kg,
    const hbf* __restrict__ vg, hbf* __restrict__ outA)
{
    __shared__ hbf sK0[64 * 64], sK1[64 * 64];   // [s][d], swizzled
    __shared__ hbf sV0[64 * 64], sV1[64 * 64];   // [d][s], swizzled
    __shared__ hbf sP[4 * 32 * 64];              // per wave [q=32][kv=64], swizzled
    const int tid = threadIdx.x, lane = tid & 63, wid = tid >> 6;
    const int lr = lane & 15, hg = lane >> 4;
    const int wg = (blockIdx.x & 7) * 96 + (blockIdx.x >> 3);   // 768/8 = 96
    const int bh = wg >> 4;
    const int b = bh / H_, h = bh - b * H_;
    const int wr0 = (wg & 15) * 128 + wid * 32;
    const hbf* qbh = qg + (size_t)bh * T_ * D_;
    const hbf* kbh = kg + (size_t)bh * T_ * D_;
    const hbf* vbh = vg + (size_t)h * 64 * BT_ + (size_t)b * T_;

    bf16x8 a_q[2][2];
#pragma unroll
    for (int m = 0; m < 2; ++m)
#pragma unroll
        for (int kf = 0; kf < 2; ++kf)
            a_q[m][kf] = *(const bf16x8*)(qbh + (size_t)(wr0 + m * 16 + lr) * D_ + kf * 32 + hg * 8);

    bf16x8 vone;
#pragma unroll
    for (int i = 0; i < 8; ++i) vone[i] = (bf16_t)1.0f;

    f32x4 o[2][4] = {};
    f32x4 lden[2] = {};            // row-sum accumulator, same layout as o
    float mreg[2] = {-3e38f, -3e38f};

    int offK[2], offV[2];
#pragma unroll
    for (int i = 0; i < 2; ++i) {
        int c = tid + i * 256;
        int sw = ((c & 7) ^ ((c >> 3) & 7)) << 4;
        offK[i] = (c >> 3) * 128 + sw;
        offV[i] = (c >> 3) * (BT_ * 2) + sw;
    }
    hbf* sPw = sP + wid * (32 * 64);
    const int sl0 = ((0 * 4 + hg) ^ (lr & 7)) << 4;
    const int sl1 = ((1 * 4 + hg) ^ (lr & 7)) << 4;
    const int bcast = hg * 20;   // source lane hg*16 + (hg*4): for fb[j] add j

    auto stage = [&](int itn, hbf* sKd, hbf* sVd) {
        const char* kp = (const char*)kbh + (size_t)itn * 8192;
        const char* vp = (const char*)vbh + (size_t)itn * 128;
#pragma unroll
        for (int i = 0; i < 2; ++i) {
            load_lds16(kp + offK[i], (char*)sKd + i * 4096 + wid * 1024);
            load_lds16(vp + offV[i], (char*)sVd + i * 4096 + wid * 1024);
        }
    };

    auto tile = [&](const hbf* sKc, const hbf* sVc) {
        f32x4 st[4][2] = {};
        __builtin_amdgcn_s_setprio(1);
#pragma unroll
        for (int kf = 0; kf < 2; ++kf) {
            const int sl = kf ? sl1 : sl0;
#pragma unroll
            for (int n = 0; n < 4; ++n) {
                bf16x8 ak = *(const bf16x8*)((const char*)sKc + (n * 16 + lr) * 128 + sl);
                st[n][0] = __builtin_amdgcn_mfma_f32_16x16x32_bf16(ak, a_q[0][kf], st[n][0], 0, 0, 0);
                st[n][1] = __builtin_amdgcn_mfma_f32_16x16x32_bf16(ak, a_q[1][kf], st[n][1], 0, 0, 0);
            }
        }
        __builtin_amdgcn_s_setprio(0);

        // balanced in-lane max trees for BOTH m-blocks (independent chains)
        float tm[2];
#pragma unroll
        for (int m = 0; m < 2; ++m) {
            f32x4 mx = st[0][m];
            mx[0] = fmaxf(mx[0], st[1][m][0]); mx[1] = fmaxf(mx[1], st[1][m][1]);
            mx[2] = fmaxf(mx[2], st[1][m][2]); mx[3] = fmaxf(mx[3], st[1][m][3]);
            f32x4 my = st[2][m];
            my[0] = fmaxf(my[0], st[3][m][0]); my[1] = fmaxf(my[1], st[3][m][1]);
            my[2] = fmaxf(my[2], st[3][m][2]); my[3] = fmaxf(my[3], st[3][m][3]);
            float t01 = fmaxf(fmaxf(mx[0], my[0]), fmaxf(mx[1], my[1]));
            float t23 = fmaxf(fmaxf(mx[2], my[2]), fmaxf(mx[3], my[3]));
            tm[m] = fmaxf(t01, t23);
        }
        // cross-lane: ±32 via permlane32_swap (VALU pipe), ±16 via one shfl;
        // both chains issued back-to-back so latencies overlap.
        {
            float a0 = tm[0], b0 = tm[0], a1 = tm[1], b1 = tm[1];
            asm volatile("v_permlane32_swap_b32 %0, %1" : "+v"(a0), "+v"(b0));
            asm volatile("v_permlane32_swap_b32 %0, %1" : "+v"(a1), "+v"(b1));
            a0 = fmaxf(a0, b0);
            a1 = fmaxf(a1, b1);
            float s0 = __shfl_xor(a0, 16, 64);
            float s1 = __shfl_xor(a1, 16, 64);
            tm[0] = fmaxf(a0, s0);
            tm[1] = fmaxf(a1, s1);
        }

#pragma unroll
        for (int m = 0; m < 2; ++m) {
            const float t = tm[m];
            if (__any(t - mreg[m] > 11.5415603f)) {   // 8*log2(e): rarely taken
                float nm = fmaxf(mreg[m], t);
                float fac = __builtin_amdgcn_exp2f(mreg[m] - nm);
                mreg[m] = nm;
                float fb[4];
#pragma unroll
                for (int j = 0; j < 4; ++j)
                    fb[j] = __shfl(fac, bcast + j, 64);
#pragma unroll
                for (int j = 0; j < 4; ++j) {
                    lden[m][j] *= fb[j];
#pragma unroll
                    for (int nd = 0; nd < 4; ++nd)
                        o[m][nd][j] *= fb[j];
                }
            }
            const int r = m * 16 + lr;
#pragma unroll
            for (int n = 0; n < 4; ++n) {
                float p0 = __builtin_amdgcn_exp2f(st[n][m][0] - mreg[m]);
                float p1 = __builtin_amdgcn_exp2f(st[n][m][1] - mreg[m]);
                float p2 = __builtin_amdgcn_exp2f(st[n][m][2] - mreg[m]);
                float p3 = __builtin_amdgcn_exp2f(st[n][m][3] - mreg[m]);
                bf16x4 w;
                w[0] = (bf16_t)p0; w[1] = (bf16_t)p1; w[2] = (bf16_t)p2; w[3] = (bf16_t)p3;
                *(bf16x4*)((char*)sPw + r * 128 +
                           (((n * 2 + (hg >> 1)) ^ (r & 7)) << 4) + ((hg & 1) * 8)) = w;
            }
        }

        // PV + MFMA row-sum (l = P.1) — P is wave-private, no block barrier
        __builtin_amdgcn_s_setprio(1);
#pragma unroll
        for (int kf = 0; kf < 2; ++kf) {
            const int sl = kf ? sl1 : sl0;
            bf16x8 ap0 = *(const bf16x8*)((const char*)sPw + lr * 128 + sl);
            bf16x8 ap1 = *(const bf16x8*)((const char*)sPw + (16 + lr) * 128 + sl);
            lden[0] = __builtin_amdgcn_mfma_f32_16x16x32_bf16(ap0, vone, lden[0], 0, 0, 0);
            lden[1] = __builtin_amdgcn_mfma_f32_16x16x32_bf16(ap1, vone, lden[1], 0, 0, 0);
#pragma unroll
            for (int nd = 0; nd < 4; ++nd) {
                bf16x8 bv = *(const bf16x8*)((const char*)sVc + (nd * 16 + lr) * 128 + sl);
                o[0][nd] = __builtin_amdgcn_mfma_f32_16x16x32_bf16(ap0, bv, o[0][nd], 0, 0, 0);
                o[1][nd] = __builtin_amdgcn_mfma_f32_16x16x32_bf16(ap1, bv, o[1][nd], 0, 0, 0);
            }
        }
        __builtin_amdgcn_s_setprio(0);
    };

    const int NT = T_ / 64;   // 32, even
    stage(0, sK0, sV0);
    __syncthreads();
    for (int it = 0; it < NT; it += 2) {
        stage(it + 1, sK1, sV1);
        tile(sK0, sV0);
        __syncthreads();
        if (it + 2 < NT) stage(it + 2, sK0, sV0);
        tile(sK1, sV1);
        __syncthreads();
    }

    // epilogue: l already in o's layout — direct rcp, no broadcast
#pragma unroll
    for (int m = 0; m < 2; ++m) {
        f32x4 rinv;
#pragma unroll
        for (int j = 0; j < 4; ++j) rinv[j] = __builtin_amdgcn_rcpf(lden[m][j]);
#pragma unroll
        for (int nd = 0; nd < 4; ++nd)
#pragma unroll
            for (int j = 0; j < 4; ++j) {
                int row = wr0 + m * 16 + hg * 4 + j;
                int col = nd * 16 + lr;
                outA[((size_t)(b * T_ + row)) * C_ + h * D_ + col] =
                    __float2bfloat16(o[m][nd][j] * rinv[j]);
            }
    }
}

// ---------------- launch ----------------
extern "C" void kernel_launch(void* const* d_in, const int* in_sizes, int n_in,
                              void* d_out, int out_size, void* d_ws, size_t ws_size,
                              hipStream_t stream)
{
    const float* x    = (const float*)d_in[0];
    const float* Wq   = (const float*)d_in[1];
    const float* Wk   = (const float*)d_in[2];
    const float* Wv   = (const float*)d_in[3];
    const float* Wo   = (const float*)d_in[4];
    const float* bo   = (const float*)d_in[5];
    const float* ln1g = (const float*)d_in[6];
    const float* ln1b = (const float*)d_in[7];
    const float* ln2g = (const float*)d_in[8];
    const float* ln2b = (const float*)d_in[9];
    const float* W1   = (const float*)d_in[10];
    const float* b1   = (const float*)d_in[11];
    const float* W2   = (const float*)d_in[12];
    const float* b2   = (const float*)d_in[13];
    float* out = (float*)d_out;
    char* ws = (char*)d_ws;

    hbf*  xn    = (hbf*)(ws + 0);            // 12.58 MB
    hbf*  WqkT  = (hbf*)(ws + 12582912);     // [2304][768] 3.54 MB (q,k,v rows)
    hbf*  qb    = (hbf*)(ws + 16121856);     // 12.58 MB
    hbf*  kb    = (hbf*)(ws + 28704768);     // 12.58 MB
    hbf*  vT    = (hbf*)(ws + 41287680);     // [768][8192] 12.58 MB
    hbf*  h1    = (hbf*)(ws + 0);            // 50.33 MB overlay (dead inputs by MLP)
    hbf*  attnB = (hbf*)(ws + 53870592);     // 12.58 MB
    hbf*  yln   = (hbf*)(ws + 53870592);     // overlays attnB
    hbf*  x2b   = (hbf*)(ws + 66453504);     // 12.58 MB (bf16 residual-1)
    hbf*  WoT   = (hbf*)(ws + 91619328);     // 1.18 MB
    hbf*  W1T   = (hbf*)(ws + 92798976);     // 4.72 MB
    hbf*  W2T   = (hbf*)(ws + 97517568);     // 4.72 MB (end 102,236,160)

    // 768^-0.5 * log2(e): QK^T scores land in log2 domain for raw v_exp_f32
    const float SCALE2 = 0.036084391824351615f * 1.4426950408889634f;

    pack_all<<<1728, 256, 0, stream>>>(Wq, Wk, Wv, Wo, W1, W2, WqkT, WoT, W1T, W2T);
    ln_kernel<float><<<8192, 192, 0, stream>>>(x, ln1g, ln1b, xn);
    gemm_kernel<3,128><<<1152, 256, 0, stream>>>(xn, WqkT, nullptr, nullptr, nullptr, nullptr,
        nullptr, 8192, 2304, 768, qb, kb, vT, SCALE2, 18);
    attn_kernel<<<768, 256, 0, stream>>>(qb, kb, vT, attnB);
    gemm_kernel<4,64><<<768, 256, 0, stream>>>(attnB, WoT, nullptr, x2b, bo, x,
        nullptr, 8192, 768, 768, nullptr, nullptr, nullptr, 1.0f, 12);
    ln_kernel<hbf><<<8192, 192, 0, stream>>>(x2b, ln2g, ln2b, yln);
    gemm_kernel<2,128><<<1536, 256, 0, stream>>>(yln, W1T, nullptr, h1, b1, nullptr,
        nullptr, 8192, 3072, 768, nullptr, nullptr, nullptr, 1.0f, 24);
    gemm_kernel<5,64><<<768, 256, 0, stream>>>(h1, W2T, out, nullptr, b2, nullptr,
        x2b, 8192, 768, 3072, nullptr, nullptr, nullptr, 1.0f, 12);
}

// Round 15
// 257.698 us; speedup vs baseline: 1.1159x; 1.0042x over previous
//
#include <hip/hip_runtime.h>
#include <hip/hip_bf16.h>
#include <cstdint>
#include <cmath>

#define B_ 4
#define T_ 2048
#define C_ 768
#define H_ 12
#define D_ 64
#define MLP_ 3072
#define BT_ (B_*T_)

typedef __hip_bfloat16 hbf;
typedef __bf16 bf16_t;
typedef bf16_t bf16x8 __attribute__((ext_vector_type(8)));
typedef bf16_t bf16x4 __attribute__((ext_vector_type(4)));
typedef float f32x4 __attribute__((ext_vector_type(4)));

static __device__ __forceinline__ void load_lds16(const void* g, void* l) {
    __builtin_amdgcn_global_load_lds(
        (const __attribute__((address_space(1))) unsigned int*)g,
        (__attribute__((address_space(3))) unsigned int*)l, 16, 0, 0);
}

// ------ merged front-end: LN1 (blocks 0..8191) + weight pack (8192..9919) ------
// pack blk' = blk-8192: [0,432) qkv, [432,576) Wo, [576,1152) W1, [1152,1728) W2.
__global__ __launch_bounds__(256) void pack_ln(
    const float* __restrict__ x, const float* __restrict__ ln1g,
    const float* __restrict__ ln1b, hbf* __restrict__ xn,
    const float* __restrict__ Wq, const float* __restrict__ Wk,
    const float* __restrict__ Wv, const float* __restrict__ Wo,
    const float* __restrict__ W1, const float* __restrict__ W2,
    hbf* __restrict__ WqkT, hbf* __restrict__ WoT,
    hbf* __restrict__ W1T, hbf* __restrict__ W2T)
{
    __shared__ float smem[64 * 65];
    const int blk = blockIdx.x;
    const int t = threadIdx.x;
    if (blk < 8192) {
        // layernorm row blk: 192 active threads (3 full waves), wave 3 idle
        const bool act = t < 192;
        float v[4] = {0, 0, 0, 0};
        if (act) {
            const float4 xv = *(const float4*)(x + (size_t)blk * C_ + t * 4);
            v[0] = xv.x; v[1] = xv.y; v[2] = xv.z; v[3] = xv.w;
        }
        float s = 0.0f, s2 = 0.0f;
#pragma unroll
        for (int k = 0; k < 4; ++k) { s += v[k]; s2 += v[k] * v[k]; }
#pragma unroll
        for (int m = 1; m < 64; m <<= 1) {
            s  += __shfl_xor(s,  m, 64);
            s2 += __shfl_xor(s2, m, 64);
        }
        if (act && (t & 63) == 0) { smem[t >> 6] = s; smem[3 + (t >> 6)] = s2; }
        __syncthreads();
        if (act) {
            float S  = smem[0] + smem[1] + smem[2];
            float S2 = smem[3] + smem[4] + smem[5];
            float mu  = S * (1.0f / C_);
            float var = S2 * (1.0f / C_) - mu * mu;
            float inv = rsqrtf(var + 1e-6f);
            const float4 gv = *(const float4*)(ln1g + t * 4);
            const float4 bv = *(const float4*)(ln1b + t * 4);
            bf16x4 o4;
            o4[0] = (bf16_t)((v[0] - mu) * inv * gv.x + bv.x);
            o4[1] = (bf16_t)((v[1] - mu) * inv * gv.y + bv.y);
            o4[2] = (bf16_t)((v[2] - mu) * inv * gv.z + bv.z);
            o4[3] = (bf16_t)((v[3] - mu) * inv * gv.w + bv.w);
            *(bf16x4*)((bf16_t*)xn + (size_t)blk * C_ + t * 4) = o4;
        }
        return;
    }
    // weight pack: 64x64 f32 tile transpose -> bf16
    const int pb = blk - 8192;
    const float* src; hbf* dst; int R, S, r0, s0;
    if (pb < 432) {
        const int z = pb / 12, y = pb - z * 12;
        const int mtx = z / 12, head = z - mtx * 12;
        src = (mtx == 0 ? Wq : mtx == 1 ? Wk : Wv) + (size_t)head * 49152;
        dst = WqkT + (size_t)z * 49152;
        R = 768; S = 64; r0 = y * 64; s0 = 0;
    } else if (pb < 576) {
        const int l = pb - 432;
        src = Wo; dst = WoT; R = 768; S = 768;
        r0 = (l / 12) * 64; s0 = (l % 12) * 64;
    } else if (pb < 1152) {
        const int l = pb - 576;
        src = W1; dst = W1T; R = 768; S = 3072;
        r0 = (l / 48) * 64; s0 = (l % 48) * 64;
    } else {
        const int l = pb - 1152;
        src = W2; dst = W2T; R = 3072; S = 768;
        r0 = (l / 12) * 64; s0 = (l % 12) * 64;
    }
    const int c = t & 63, q = t >> 6;
#pragma unroll
    for (int j = 0; j < 16; ++j) {
        int r = q + j * 4;
        smem[r * 65 + c] = src[(size_t)(r0 + r) * S + s0 + c];
    }
    __syncthreads();
#pragma unroll
    for (int j = 0; j < 16; ++j) {
        int s = q + j * 4;
        dst[(size_t)(s0 + s) * R + r0 + c] = __float2bfloat16(smem[c * 65 + s]);
    }
}

// ---------------- layernorm (row = 768), vectorized: 192 thr x 4 elems --------
template<typename TI>
__global__ __launch_bounds__(192) void ln_kernel(
    const TI* __restrict__ x, const float* __restrict__ g,
    const float* __restrict__ bb, hbf* __restrict__ out)
{
    __shared__ float red[6];
    const int row = blockIdx.x;
    const int t = threadIdx.x;
    float v[4];
    if constexpr (__is_same(TI, float)) {
        const float4 xv = *(const float4*)(x + (size_t)row * C_ + t * 4);
        v[0] = xv.x; v[1] = xv.y; v[2] = xv.z; v[3] = xv.w;
    } else {
        bf16x4 xv = *(const bf16x4*)((const bf16_t*)x + (size_t)row * C_ + t * 4);
#pragma unroll
        for (int k = 0; k < 4; ++k) v[k] = (float)xv[k];
    }
    float s = 0.0f, s2 = 0.0f;
#pragma unroll
    for (int k = 0; k < 4; ++k) { s += v[k]; s2 += v[k] * v[k]; }
#pragma unroll
    for (int m = 1; m < 64; m <<= 1) {
        s  += __shfl_xor(s,  m, 64);
        s2 += __shfl_xor(s2, m, 64);
    }
    if ((t & 63) == 0) { red[t >> 6] = s; red[3 + (t >> 6)] = s2; }
    __syncthreads();
    float S  = red[0] + red[1] + red[2];
    float S2 = red[3] + red[4] + red[5];
    float mu  = S * (1.0f / C_);
    float var = S2 * (1.0f / C_) - mu * mu;
    float inv = rsqrtf(var + 1e-6f);
    const float4 gv = *(const float4*)(g  + t * 4);
    const float4 bv = *(const float4*)(bb + t * 4);
    bf16x4 o4;
    o4[0] = (bf16_t)((v[0] - mu) * inv * gv.x + bv.x);
    o4[1] = (bf16_t)((v[1] - mu) * inv * gv.y + bv.y);
    o4[2] = (bf16_t)((v[2] - mu) * inv * gv.z + bv.z);
    o4[3] = (bf16_t)((v[3] - mu) * inv * gv.w + bv.w);
    *(bf16x4*)((bf16_t*)out + (size_t)row * C_ + t * 4) = o4;
}

// ---------------- GEMM: C[M,N] = A[M,K](bf16) * Bt[N,K](bf16)^T ----------------
// BK=64, tile 128xTN (TN=128 or 64), XOR-swizzled LDS, SINGLE buffer,
// 2-barrier loop, 1D grid + XCD swizzle, 4 blocks/CU.
// (r11 dbuf regression locked out.)
template<int EPI, int TN>
__global__ __launch_bounds__(256, 4) void gemm_kernel(
    const hbf* __restrict__ A, const hbf* __restrict__ Bt,
    float* __restrict__ outF, hbf* __restrict__ outH,
    const float* __restrict__ bias, const float* __restrict__ residF,
    const hbf* __restrict__ residH,
    int M, int N, int K,
    hbf* __restrict__ qb, hbf* __restrict__ kb, hbf* __restrict__ vt,
    float scale, int gx)
{
    constexpr int AM = (TN == 128) ? 4 : 2;     // m-frags per wave
    constexpr int NB_B = (TN == 128) ? 4 : 2;   // B staging iters
    __shared__ hbf sA[128 * 64];
    __shared__ hbf sB[TN * 64];
    const int tid = threadIdx.x;
    const int lane = tid & 63;
    const int wid = tid >> 6;
    const int lr = lane & 15, hg = lane >> 4;
    const int bid = blockIdx.x, nwg = gridDim.x;
    const int wg = (bid & 7) * (nwg >> 3) + (bid >> 3);
    const int bx = wg % gx, by = wg / gx;
    const int row0 = by * 128;
    const int col0 = bx * TN;
    const int wrow = (TN == 128) ? (wid >> 1) * 64 : wid * 32;
    const int wcol = (TN == 128) ? (wid & 1) * 64 : 0;

    f32x4 acc[AM][4] = {};

    int offG[4];
    const int Kb = K * 2;
#pragma unroll
    for (int i = 0; i < 4; ++i) {
        int c = tid + i * 256;
        offG[i] = (c >> 3) * Kb + (((c & 7) ^ ((c >> 3) & 7)) << 4);
    }
    const char* gA = (const char*)(A + (size_t)row0 * K);
    const char* gB = (const char*)(Bt + (size_t)col0 * K);

    auto stage = [&](int kt) {
        const int kb2 = kt * 128;
#pragma unroll
        for (int i = 0; i < 4; ++i)
            load_lds16(gA + (size_t)(offG[i] + kb2), (char*)sA + i * 4096 + wid * 1024);
#pragma unroll
        for (int i = 0; i < NB_B; ++i)
            load_lds16(gB + (size_t)(offG[i] + kb2), (char*)sB + i * 4096 + wid * 1024);
    };

    const int NK = K >> 6;
    stage(0);
    for (int kt = 0; kt < NK; ++kt) {
        __syncthreads();   // drains staged loads
#pragma unroll
        for (int kf = 0; kf < 2; ++kf) {
            const int sl = ((kf * 4 + hg) ^ (lr & 7)) << 4;
            bf16x8 af[AM], bfr[4];
#pragma unroll
            for (int m = 0; m < AM; ++m)
                af[m] = *(const bf16x8*)((const char*)sA + (wrow + m * 16 + lr) * 128 + sl);
#pragma unroll
            for (int n = 0; n < 4; ++n)
                bfr[n] = *(const bf16x8*)((const char*)sB + (wcol + n * 16 + lr) * 128 + sl);
#pragma unroll
            for (int m = 0; m < AM; ++m)
#pragma unroll
                for (int n = 0; n < 4; ++n)
                    acc[m][n] = __builtin_amdgcn_mfma_f32_16x16x32_bf16(af[m], bfr[n], acc[m][n], 0, 0, 0);
        }
        __syncthreads();   // all waves done reading before restage
        if (kt + 1 < NK) stage(kt + 1);
    }

#pragma unroll
    for (int m = 0; m < AM; ++m) {
#pragma unroll
        for (int n = 0; n < 4; ++n) {
            const int colc = col0 + wcol + n * 16 + lr;
            const int rowb = row0 + wrow + m * 16 + hg * 4;
            if constexpr (EPI == 3) {
                if (colc >= 2 * C_) {
                    bf16x4 w;
#pragma unroll
                    for (int j = 0; j < 4; ++j) w[j] = (bf16_t)acc[m][n][j];
                    *(bf16x4*)(vt + (size_t)(colc - 2 * C_) * BT_ + rowb) = w;
                    continue;
                }
            }
#pragma unroll
            for (int j = 0; j < 4; ++j) {
                int row = rowb + j;
                int col = colc;
                float v = acc[m][n][j];
                if constexpr (EPI == 0) {
                    outH[(size_t)row * N + col] = __float2bfloat16(v);
                } else if constexpr (EPI == 2) {
                    // tanh-form GELU: ge = t*e/(e+1), e = exp2(2.3021142*t + 0.10294234*t^3)
                    float tt = v + bias[col];
                    float t3 = tt * tt * tt;
                    float z = fminf(fmaf(t3, 0.1029423372f, 2.3021141876f * tt), 126.0f);
                    float e = __builtin_amdgcn_exp2f(z);
                    float ge = tt * e * __builtin_amdgcn_rcpf(e + 1.0f);
                    outH[(size_t)row * N + col] = __float2bfloat16(ge);
                } else if constexpr (EPI == 3) {
                    int typ = col / C_;            // 0=q, 1=k (v handled above)
                    int rr = col - typ * C_;
                    int h = rr >> 6, d = rr & 63;
                    int b = row >> 11, t = row & (T_ - 1);
                    size_t bh = (size_t)b * H_ + h;
                    if (typ == 0) qb[(bh * T_ + t) * D_ + d] = __float2bfloat16(v * scale);
                    else          kb[(bh * T_ + t) * D_ + d] = __float2bfloat16(v);
                } else if constexpr (EPI == 4) {
                    outH[(size_t)row * N + col] =
                        __float2bfloat16(v + bias[col] + residF[(size_t)row * N + col]);
                } else {  // EPI == 5
                    outF[(size_t)row * N + col] =
                        v + bias[col] + __bfloat162float(residH[(size_t)row * N + col]);
                }
            }
        }
    }
}

// ---------------- flash attention (swapped QK^T, defer-max, raw exp2) ----------
// 1D grid 768 (XCD-swizzled). 4 waves x 32 q-rows. q pre-scaled by
// 768^-0.5 * log2(e). T15-lite schedule: QK -> V-frag hoist -> SM(m0) ->
// PV(m0) -> SM(m1) -> PV(m1): PV(m0)'s MFMAs execute under SM(m1)'s VALU.
// Denominator l = P.1 via MFMA ones-fragment (layout matches o; no broadcasts).
__global__ __launch_bounds__(256, 3) void attn_kernel(
    const hbf* __restrict__ qg, const hbf* __restrict__ kg,
    const hbf* __restrict__ vg, hbf* __restrict__ outA)
{
    __shared__ hbf sK0[64 * 64], sK1[64 * 64];   // [s][d], swizzled
    __shared__ hbf sV0[64 * 64], sV1[64 * 64];   // [d][s], swizzled
    __shared__ hbf sP[4 * 32 * 64];              // per wave [q=32][kv=64], swizzled
    const int tid = threadIdx.x, lane = tid & 63, wid = tid >> 6;
    const int lr = lane & 15, hg = lane >> 4;
    const int wg = (blockIdx.x & 7) * 96 + (blockIdx.x >> 3);   // 768/8 = 96
    const int bh = wg >> 4;
    const int b = bh / H_, h = bh - b * H_;
    const int wr0 = (wg & 15) * 128 + wid * 32;
    const hbf* qbh = qg + (size_t)bh * T_ * D_;
    const hbf* kbh = kg + (size_t)bh * T_ * D_;
    const hbf* vbh = vg + (size_t)h * 64 * BT_ + (size_t)b * T_;

    bf16x8 a_q[2][2];
#pragma unroll
    for (int m = 0; m < 2; ++m)
#pragma unroll
        for (int kf = 0; kf < 2; ++kf)
            a_q[m][kf] = *(const bf16x8*)(qbh + (size_t)(wr0 + m * 16 + lr) * D_ + kf * 32 + hg * 8);

    bf16x8 vone;
#pragma unroll
    for (int i = 0; i < 8; ++i) vone[i] = (bf16_t)1.0f;

    f32x4 o[2][4] = {};
    f32x4 lden[2] = {};            // row-sum accumulator, same layout as o
    float mreg[2] = {-3e38f, -3e38f};

    int offK[2], offV[2];
#pragma unroll
    for (int i = 0; i < 2; ++i) {
        int c = tid + i * 256;
        int sw = ((c & 7) ^ ((c >> 3) & 7)) << 4;
        offK[i] = (c >> 3) * 128 + sw;
        offV[i] = (c >> 3) * (BT_ * 2) + sw;
    }
    hbf* sPw = sP + wid * (32 * 64);
    const int sl0 = ((0 * 4 + hg) ^ (lr & 7)) << 4;
    const int sl1 = ((1 * 4 + hg) ^ (lr & 7)) << 4;
    const int bcast = hg * 20;   // source lane hg*16 + (hg*4): for fb[j] add j

    auto stage = [&](int itn, hbf* sKd, hbf* sVd) {
        const char* kp = (const char*)kbh + (size_t)itn * 8192;
        const char* vp = (const char*)vbh + (size_t)itn * 128;
#pragma unroll
        for (int i = 0; i < 2; ++i) {
            load_lds16(kp + offK[i], (char*)sKd + i * 4096 + wid * 1024);
            load_lds16(vp + offV[i], (char*)sVd + i * 4096 + wid * 1024);
        }
    };

// per-m softmax: defer-max rescale + 16 exps + sP row write (m is a literal)
#define SOFTMAX_M(m, tmv)                                                      \
    {                                                                          \
        if (__any((tmv) - mreg[m] > 11.5415603f)) {                            \
            float nm = fmaxf(mreg[m], (tmv));                                  \
            float fac = __builtin_amdgcn_exp2f(mreg[m] - nm);                  \
            mreg[m] = nm;                                                      \
            float fb[4];                                                       \
            _Pragma("unroll")                                                  \
            for (int j = 0; j < 4; ++j) fb[j] = __shfl(fac, bcast + j, 64);    \
            _Pragma("unroll")                                                  \
            for (int j = 0; j < 4; ++j) {                                      \
                lden[m][j] *= fb[j];                                           \
                _Pragma("unroll")                                              \
                for (int nd = 0; nd < 4; ++nd) o[m][nd][j] *= fb[j];           \
            }                                                                  \
        }                                                                      \
        const int r = (m) * 16 + lr;                                           \
        _Pragma("unroll")                                                      \
        for (int n = 0; n < 4; ++n) {                                          \
            float p0 = __builtin_amdgcn_exp2f(st[n][m][0] - mreg[m]);          \
            float p1 = __builtin_amdgcn_exp2f(st[n][m][1] - mreg[m]);          \
            float p2 = __builtin_amdgcn_exp2f(st[n][m][2] - mreg[m]);          \
            float p3 = __builtin_amdgcn_exp2f(st[n][m][3] - mreg[m]);          \
            bf16x4 w;                                                          \
            w[0] = (bf16_t)p0; w[1] = (bf16_t)p1;                              \
            w[2] = (bf16_t)p2; w[3] = (bf16_t)p3;                              \
            *(bf16x4*)((char*)sPw + r * 128 +                                  \
                       (((n * 2 + (hg >> 1)) ^ (r & 7)) << 4) +                \
                       ((hg & 1) * 8)) = w;                                    \
        }                                                                      \
    }

// per-m PV + row-sum from sP rows [m*16 .. m*16+15] (wave-private, DS in-order)
#define PV_M(m)                                                                \
    __builtin_amdgcn_s_setprio(1);                                             \
    _Pragma("unroll")                                                          \
    for (int kf = 0; kf < 2; ++kf) {                                           \
        const int sl = kf ? sl1 : sl0;                                         \
        bf16x8 ap = *(const bf16x8*)((const char*)sPw + ((m) * 16 + lr) * 128 + sl); \
        lden[m] = __builtin_amdgcn_mfma_f32_16x16x32_bf16(ap, vone, lden[m], 0, 0, 0); \
        _Pragma("unroll")                                                      \
        for (int nd = 0; nd < 4; ++nd)                                         \
            o[m][nd] = __builtin_amdgcn_mfma_f32_16x16x32_bf16(ap, bvr[kf][nd], o[m][nd], 0, 0, 0); \
    }                                                                          \
    __builtin_amdgcn_s_setprio(0);

    auto tile = [&](const hbf* sKc, const hbf* sVc) {
        f32x4 st[4][2] = {};
        __builtin_amdgcn_s_setprio(1);
#pragma unroll
        for (int kf = 0; kf < 2; ++kf) {
            const int sl = kf ? sl1 : sl0;
#pragma unroll
            for (int n = 0; n < 4; ++n) {
                bf16x8 ak = *(const bf16x8*)((const char*)sKc + (n * 16 + lr) * 128 + sl);
                st[n][0] = __builtin_amdgcn_mfma_f32_16x16x32_bf16(ak, a_q[0][kf], st[n][0], 0, 0, 0);
                st[n][1] = __builtin_amdgcn_mfma_f32_16x16x32_bf16(ak, a_q[1][kf], st[n][1], 0, 0, 0);
            }
        }
        __builtin_amdgcn_s_setprio(0);

        // hoist V fragments: ds_reads issued now, consumed after softmax
        bf16x8 bvr[2][4];
#pragma unroll
        for (int kf = 0; kf < 2; ++kf) {
            const int sl = kf ? sl1 : sl0;
#pragma unroll
            for (int nd = 0; nd < 4; ++nd)
                bvr[kf][nd] = *(const bf16x8*)((const char*)sVc + (nd * 16 + lr) * 128 + sl);
        }

        // balanced in-lane max trees for BOTH m-blocks (independent chains)
        float tm[2];
#pragma unroll
        for (int m = 0; m < 2; ++m) {
            f32x4 mx = st[0][m];
            mx[0] = fmaxf(mx[0], st[1][m][0]); mx[1] = fmaxf(mx[1], st[1][m][1]);
            mx[2] = fmaxf(mx[2], st[1][m][2]); mx[3] = fmaxf(mx[3], st[1][m][3]);
            f32x4 my = st[2][m];
            my[0] = fmaxf(my[0], st[3][m][0]); my[1] = fmaxf(my[1], st[3][m][1]);
            my[2] = fmaxf(my[2], st[3][m][2]); my[3] = fmaxf(my[3], st[3][m][3]);
            float t01 = fmaxf(fmaxf(mx[0], my[0]), fmaxf(mx[1], my[1]));
            float t23 = fmaxf(fmaxf(mx[2], my[2]), fmaxf(mx[3], my[3]));
            tm[m] = fmaxf(t01, t23);
        }
        // cross-lane: ±32 via permlane32_swap (VALU pipe), ±16 via one shfl;
        // both chains issued back-to-back so latencies overlap.
        {
            float a0 = tm[0], b0 = tm[0], a1 = tm[1], b1 = tm[1];
            asm volatile("v_permlane32_swap_b32 %0, %1" : "+v"(a0), "+v"(b0));
            asm volatile("v_permlane32_swap_b32 %0, %1" : "+v"(a1), "+v"(b1));
            a0 = fmaxf(a0, b0);
            a1 = fmaxf(a1, b1);
            float s0 = __shfl_xor(a0, 16, 64);
            float s1 = __shfl_xor(a1, 16, 64);
            tm[0] = fmaxf(a0, s0);
            tm[1] = fmaxf(a1, s1);
        }

        // interleaved: PV(m0) MFMAs run under SM(m1)'s VALU
        SOFTMAX_M(0, tm[0]);
        PV_M(0);
        SOFTMAX_M(1, tm[1]);
        PV_M(1);
    };

    const int NT = T_ / 64;   // 32, even
    stage(0, sK0, sV0);
    __syncthreads();
    for (int it = 0; it < NT; it += 2) {
        stage(it + 1, sK1, sV1);
        tile(sK0, sV0);
        __syncthreads();
        if (it + 2 < NT) stage(it + 2, sK0, sV0);
        tile(sK1, sV1);
        __syncthreads();
    }

    // epilogue: l already in o's layout — direct rcp, no broadcast
#pragma unroll
    for (int m = 0; m < 2; ++m) {
        f32x4 rinv;
#pragma unroll
        for (int j = 0; j < 4; ++j) rinv[j] = __builtin_amdgcn_rcpf(lden[m][j]);
#pragma unroll
        for (int nd = 0; nd < 4; ++nd)
#pragma unroll
            for (int j = 0; j < 4; ++j) {
                int row = wr0 + m * 16 + hg * 4 + j;
                int col = nd * 16 + lr;
                outA[((size_t)(b * T_ + row)) * C_ + h * D_ + col] =
                    __float2bfloat16(o[m][nd][j] * rinv[j]);
            }
    }
#undef SOFTMAX_M
#undef PV_M
}

// ---------------- launch ----------------
extern "C" void kernel_launch(void* const* d_in, const int* in_sizes, int n_in,
                              void* d_out, int out_size, void* d_ws, size_t ws_size,
                              hipStream_t stream)
{
    const float* x    = (const float*)d_in[0];
    const float* Wq   = (const float*)d_in[1];
    const float* Wk   = (const float*)d_in[2];
    const float* Wv   = (const float*)d_in[3];
    const float* Wo   = (const float*)d_in[4];
    const float* bo   = (const float*)d_in[5];
    const float* ln1g = (const float*)d_in[6];
    const float* ln1b = (const float*)d_in[7];
    const float* ln2g = (const float*)d_in[8];
    const float* ln2b = (const float*)d_in[9];
    const float* W1   = (const float*)d_in[10];
    const float* b1   = (const float*)d_in[11];
    const float* W2   = (const float*)d_in[12];
    const float* b2   = (const float*)d_in[13];
    float* out = (float*)d_out;
    char* ws = (char*)d_ws;

    hbf*  xn    = (hbf*)(ws + 0);            // 12.58 MB
    hbf*  WqkT  = (hbf*)(ws + 12582912);     // [2304][768] 3.54 MB (q,k,v rows)
    hbf*  qb    = (hbf*)(ws + 16121856);     // 12.58 MB
    hbf*  kb    = (hbf*)(ws + 28704768);     // 12.58 MB
    hbf*  vT    = (hbf*)(ws + 41287680);     // [768][8192] 12.58 MB
    hbf*  h1    = (hbf*)(ws + 0);            // 50.33 MB overlay (dead inputs by MLP)
    hbf*  attnB = (hbf*)(ws + 53870592);     // 12.58 MB
    hbf*  yln   = (hbf*)(ws + 53870592);     // overlays attnB
    hbf*  x2b   = (hbf*)(ws + 66453504);     // 12.58 MB (bf16 residual-1)
    hbf*  WoT   = (hbf*)(ws + 91619328);     // 1.18 MB
    hbf*  W1T   = (hbf*)(ws + 92798976);     // 4.72 MB
    hbf*  W2T   = (hbf*)(ws + 97517568);     // 4.72 MB (end 102,236,160)

    // 768^-0.5 * log2(e): QK^T scores land in log2 domain for raw v_exp_f32
    const float SCALE2 = 0.036084391824351615f * 1.4426950408889634f;

    pack_ln<<<9920, 256, 0, stream>>>(x, ln1g, ln1b, xn,
        Wq, Wk, Wv, Wo, W1, W2, WqkT, WoT, W1T, W2T);
    gemm_kernel<3,128><<<1152, 256, 0, stream>>>(xn, WqkT, nullptr, nullptr, nullptr, nullptr,
        nullptr, 8192, 2304, 768, qb, kb, vT, SCALE2, 18);
    attn_kernel<<<768, 256, 0, stream>>>(qb, kb, vT, attnB);
    gemm_kernel<4,64><<<768, 256, 0, stream>>>(attnB, WoT, nullptr, x2b, bo, x,
        nullptr, 8192, 768, 768, nullptr, nullptr, nullptr, 1.0f, 12);
    ln_kernel<hbf><<<8192, 192, 0, stream>>>(x2b, ln2g, ln2b, yln);
    gemm_kernel<2,128><<<1536, 256, 0, stream>>>(yln, W1T, nullptr, h1, b1, nullptr,
        nullptr, 8192, 3072, 768, nullptr, nullptr, nullptr, 1.0f, 24);
    gemm_kernel<5,64><<<768, 256, 0, stream>>>(h1, W2T, out, nullptr, b2, nullptr,
        x2b, 8192, 768, 3072, nullptr, nullptr, nullptr, 1.0f, 12);
}